// Round 5
// baseline (2848.386 us; speedup 1.0000x reference)
//
#include <hip/hip_runtime.h>
#include <cstdint>
#include <cstddef>

// ---------------- problem constants ----------------
constexpr int Nn  = 200000;
constexpr int Ee  = 1600000;
constexpr int EPp = 1000000;

typedef __attribute__((ext_vector_type(8))) short bf8_t;
typedef __attribute__((ext_vector_type(4))) float f4_t;

__device__ inline unsigned short f2bf(float f) {
  union { float f; unsigned u; } v; v.f = f;
  unsigned r = v.u + 0x7FFFu + ((v.u >> 16) & 1u);
  return (unsigned short)(r >> 16);
}
__device__ inline float bf2f(unsigned short u) {
  union { unsigned u; float f; } v; v.u = ((unsigned)u) << 16;
  return v.f;
}
__device__ inline float gelu_f(float v) {
  return 0.5f * v * (1.0f + erff(v * 0.70710678118654752f));
}

// ---------------- degree / CSR build ----------------

__global__ __launch_bounds__(256) void k_degi(const int* __restrict__ dst,
                                              int* __restrict__ cnt, int E) {
  int i = blockIdx.x * 256 + threadIdx.x;
  if (i < E) atomicAdd(&cnt[dst[i]], 1);
}

__global__ __launch_bounds__(256) void k_rdeg(const int* __restrict__ cnt,
                                              float* __restrict__ rdeg, int n) {
  int i = blockIdx.x * 256 + threadIdx.x;
  if (i < n) rdeg[i] = 1.0f / (float)(cnt[i] > 1 ? cnt[i] : 1);
}

__global__ __launch_bounds__(256) void k_scan1(const int* __restrict__ in,
                                               int* __restrict__ out,
                                               int* __restrict__ bsum, int n) {
  __shared__ int sd[256];
  int t = threadIdx.x;
  int base = blockIdx.x * 1024 + t * 4;
  int v[4]; int ts = 0;
  #pragma unroll
  for (int j = 0; j < 4; ++j) { v[j] = (base + j < n) ? in[base + j] : 0; ts += v[j]; }
  sd[t] = ts; __syncthreads();
  for (int off = 1; off < 256; off <<= 1) {
    int x = (t >= off) ? sd[t - off] : 0;
    __syncthreads();
    sd[t] += x;
    __syncthreads();
  }
  int excl = sd[t] - ts;
  #pragma unroll
  for (int j = 0; j < 4; ++j) { if (base + j < n) out[base + j] = excl; excl += v[j]; }
  if (t == 255) bsum[blockIdx.x] = sd[255];
}

__global__ void k_scan2(int* bsum, int nb) {
  __shared__ int sd[256];
  int t = threadIdx.x;
  int v = (t < nb) ? bsum[t] : 0;
  sd[t] = v; __syncthreads();
  for (int off = 1; off < 256; off <<= 1) {
    int x = (t >= off) ? sd[t - off] : 0;
    __syncthreads();
    sd[t] += x;
    __syncthreads();
  }
  if (t < nb) bsum[t] = sd[t] - v;
}

__global__ __launch_bounds__(256) void k_scan3(const int* __restrict__ part,
                                               const int* __restrict__ bsum,
                                               int* __restrict__ rowptr,
                                               int* __restrict__ cursor,
                                               int n, int total) {
  int i = blockIdx.x * 256 + threadIdx.x;
  if (i == 0) rowptr[n] = total;
  if (i < n) { int v = part[i] + bsum[i >> 10]; rowptr[i] = v; cursor[i] = v; }
}

__global__ __launch_bounds__(256) void k_fill(const int* __restrict__ src,
                                              const int* __restrict__ dst,
                                              int* __restrict__ cursor,
                                              int* __restrict__ colidx, int E) {
  int e = blockIdx.x * 256 + threadIdx.x;
  if (e >= E) return;
  int pos = atomicAdd(&cursor[dst[e]], 1);
  colidx[pos] = src[e];
}

// gather-mean over bf16 features: one wave per node, 8 groups of 8 lanes
// (8 edges in flight). x rows bf16 stride ldx shorts; agg bf16 [n,64].
__global__ __launch_bounds__(256) void k_gather(const unsigned short* __restrict__ x, int ldx,
                                                const int* __restrict__ rowptr,
                                                const int* __restrict__ colidx,
                                                const float* __restrict__ rdeg,
                                                unsigned short* __restrict__ agg, int n) {
  int wave = threadIdx.x >> 6, lane = threadIdx.x & 63;
  int node = blockIdx.x * 4 + wave;
  if (node >= n) return;
  int grp = lane >> 3, c = (lane & 7) * 8;
  int r0 = rowptr[node], r1 = rowptr[node + 1];
  float s[8] = {0.f, 0.f, 0.f, 0.f, 0.f, 0.f, 0.f, 0.f};
  for (int j = r0 + grp; j < r1; j += 8) {
    bf8_t v = *(const bf8_t*)(x + (size_t)colidx[j] * ldx + c);
    #pragma unroll
    for (int jj = 0; jj < 8; ++jj) s[jj] += bf2f((unsigned short)v[jj]);
  }
  #pragma unroll
  for (int jj = 0; jj < 8; ++jj) {
    s[jj] += __shfl_xor(s[jj], 8, 64);
    s[jj] += __shfl_xor(s[jj], 16, 64);
    s[jj] += __shfl_xor(s[jj], 32, 64);
  }
  if (grp == 0) {
    float r = rdeg[node];
    bf8_t o;
    #pragma unroll
    for (int jj = 0; jj < 8; ++jj) o[jj] = (short)f2bf(s[jj] * r);
    *(bf8_t*)(agg + (size_t)node * 64 + c) = o;
  }
}

// ---------------- misc small kernels ----------------

__global__ __launch_bounds__(256) void k_cvt(const float* __restrict__ in,
                                             unsigned short* __restrict__ out, int n) {
  int i = blockIdx.x * 256 + threadIdx.x;
  if (i < n) out[i] = f2bf(in[i]);
}

// transpose + cvt weights: W[K][N] fp32 -> Wt[Npad][K] bf16 (zero-fill n>=N)
__global__ __launch_bounds__(256) void k_wt2(const float* __restrict__ W,
                                             unsigned short* __restrict__ Wt,
                                             int K, int N, int total) {
  int i = blockIdx.x * 256 + threadIdx.x;
  if (i >= total) return;
  int n = i / K, k = i - n * K;
  float v = (n < N) ? W[(size_t)k * N + n] : 0.f;
  Wt[i] = f2bf(v);
}

// SAGE weights: Wt[l][n][k] = (k<64 ? Wl[l][k][n] : Wr[l][k-64][n])
__global__ __launch_bounds__(256) void k_wtsage(const float* __restrict__ Wl,
                                                const float* __restrict__ Wr,
                                                unsigned short* __restrict__ Wt) {
  int i = blockIdx.x * 256 + threadIdx.x;
  if (i >= 3 * 64 * 128) return;
  int l = i >> 13, r = i & 8191, n = r >> 7, k = r & 127;
  float v = (k < 64) ? Wl[l * 4096 + k * 64 + n] : Wr[l * 4096 + (k - 64) * 64 + n];
  Wt[i] = f2bf(v);
}

__global__ __launch_bounds__(256) void k_stats(const float* __restrict__ h,
                                               float* __restrict__ stats, int n) {
  int lane = threadIdx.x & 63, grp = threadIdx.x >> 6;
  float s = 0.f, s2 = 0.f;
  for (int r = blockIdx.x * 4 + grp; r < n; r += gridDim.x * 4) {
    float v = h[(size_t)r * 64 + lane];
    s += v; s2 += v * v;
  }
  __shared__ float l1[4][64], l2[4][64];
  l1[grp][lane] = s; l2[grp][lane] = s2;
  __syncthreads();
  if (grp == 0) {
    s  = l1[0][lane] + l1[1][lane] + l1[2][lane] + l1[3][lane];
    s2 = l2[0][lane] + l2[1][lane] + l2[2][lane] + l2[3][lane];
    atomicAdd(&stats[lane], s);
    atomicAdd(&stats[64 + lane], s2);
  }
}

__global__ void k_statfin(float* stats, const float* __restrict__ ms_, int n) {
  int d = threadIdx.x;
  if (d < 64) {
    float invn = 1.0f / (float)n;
    float m  = stats[d] * invn;
    float e2 = stats[64 + d] * invn;
    float ms = ms_[d];
    float var = e2 - (2.0f * ms - ms * ms) * m * m;
    stats[128 + d] = ms * m;
    stats[192 + d] = rsqrtf(var + 1e-5f);
  }
}

// graph_norm apply + residual; write bf16 z column (row stride 192 shorts)
__global__ __launch_bounds__(256) void k_norm(const float* __restrict__ h,
                                              const float* __restrict__ stats,
                                              const float* __restrict__ w,
                                              const float* __restrict__ b,
                                              unsigned short* __restrict__ zcol,
                                              const unsigned short* __restrict__ prev, int n) {
  int i = blockIdx.x * 256 + threadIdx.x;
  if (i >= n * 64) return;
  int r = i >> 6, d = i & 63;
  float v = (h[i] - stats[128 + d]) * stats[192 + d] * w[d] + b[d];
  if (prev) v += bf2f(prev[(size_t)r * 192 + d]);
  zcol[(size_t)r * 192 + d] = f2bf(v);
}

// ---------------- generic bf16 MFMA GEMM (barrier-free, for SAGE) ----------------
template <int NT>
__global__ __launch_bounds__(256) void mgemm(
    const void* __restrict__ A1, int lda1,
    const void* __restrict__ A2, int lda2, int K1, int a_bf16,
    const unsigned short* __restrict__ Wt,
    const float* __restrict__ bias,
    void* __restrict__ Cout, int ldc, int c_bf16, int act,
    int M, int K, int N) {
  int lane = threadIdx.x & 63, wave = threadIdx.x >> 6;
  int quad = lane >> 4, col = lane & 15;
  int row0 = blockIdx.x * 128 + wave * 32;
  int n_base = blockIdx.y * NT * 16;

  f4_t acc[2][NT];
  #pragma unroll
  for (int mt = 0; mt < 2; ++mt)
    #pragma unroll
    for (int nt = 0; nt < NT; ++nt) acc[mt][nt] = (f4_t)0.f;

  int gm[2];
  gm[0] = row0 + col;      if (gm[0] >= M) gm[0] = M - 1;
  gm[1] = row0 + 16 + col; if (gm[1] >= M) gm[1] = M - 1;

  for (int kc0 = 0; kc0 < K; kc0 += 32) {
    int kc = kc0 + quad * 8;
    bf8_t a[2];
    #pragma unroll
    for (int mt = 0; mt < 2; ++mt) {
      const void* src; size_t off;
      if (kc < K1) { src = A1; off = (size_t)gm[mt] * lda1 + kc; }
      else         { src = A2; off = (size_t)gm[mt] * lda2 + kc - K1; }
      if (a_bf16) {
        a[mt] = *(const bf8_t*)((const unsigned short*)src + off);
      } else {
        const float* p = (const float*)src + off;
        float4 f0 = *(const float4*)p;
        float4 f1 = *(const float4*)(p + 4);
        float ff[8] = {f0.x, f0.y, f0.z, f0.w, f1.x, f1.y, f1.z, f1.w};
        #pragma unroll
        for (int j = 0; j < 8; ++j) a[mt][j] = (short)f2bf(ff[j]);
      }
    }
    #pragma unroll
    for (int nt = 0; nt < NT; ++nt) {
      bf8_t b = *(const bf8_t*)(Wt + (size_t)(n_base + nt * 16 + col) * K + kc);
      acc[0][nt] = __builtin_amdgcn_mfma_f32_16x16x32_bf16(a[0], b, acc[0][nt], 0, 0, 0);
      acc[1][nt] = __builtin_amdgcn_mfma_f32_16x16x32_bf16(a[1], b, acc[1][nt], 0, 0, 0);
    }
  }

  #pragma unroll
  for (int nt = 0; nt < NT; ++nt) {
    int n = n_base + nt * 16 + col;
    float bs = (bias && n < N) ? bias[n] : 0.f;
    #pragma unroll
    for (int mt = 0; mt < 2; ++mt)
      #pragma unroll
      for (int r = 0; r < 4; ++r) {
        int row = row0 + mt * 16 + quad * 4 + r;
        if (row >= M || n >= N) continue;
        float v = acc[mt][nt][r] + bs;
        if (act) v = gelu_f(v);
        if (c_bf16) ((unsigned short*)Cout)[(size_t)row * ldc + n] = f2bf(v);
        else        ((float*)Cout)[(size_t)row * ldc + n] = v;
      }
  }
}

// ---------------- fused node megakernel ----------------
// One wave per 16 rows: dyt1 -> lin1 -> lin2 -> lin3 -> dyt2+resid+rownorm ->
// adyt1 -> aa1 -> aa2 -> aa3 -> adyt2 -> aa4 -> log_softmax.
// Per-wave private LDS tile; NO barriers (in-wave DS ordering).
__global__ __launch_bounds__(256) void k_node(
    const unsigned short* __restrict__ z_bf,
    const float* __restrict__ x_res,
    const float* __restrict__ d1w, const float* __restrict__ d1b, const float* __restrict__ d1a,
    const unsigned short* __restrict__ wt1, const float* __restrict__ b1,
    const unsigned short* __restrict__ wt2, const float* __restrict__ b2,
    const unsigned short* __restrict__ wt3, const float* __restrict__ b3,
    const float* __restrict__ d2w, const float* __restrict__ d2b, const float* __restrict__ d2a,
    const float* __restrict__ a1w, const float* __restrict__ a1b, const float* __restrict__ a1a,
    const unsigned short* __restrict__ wa1, const float* __restrict__ ba1,
    const unsigned short* __restrict__ wa2, const float* __restrict__ ba2,
    const unsigned short* __restrict__ wa3, const float* __restrict__ ba3,
    const float* __restrict__ a2w, const float* __restrict__ a2b, const float* __restrict__ a2a,
    const unsigned short* __restrict__ wa4, const float* __restrict__ ba4,
    unsigned short* __restrict__ zn_bf,
    float* __restrict__ out, int M) {
  __shared__ unsigned short hs[4][16][264];
  int lane = threadIdx.x & 63, wave = threadIdx.x >> 6;
  int quad = lane >> 4, col = lane & 15;
  int row0 = blockIdx.x * 64 + wave * 16;
  unsigned short (*h)[264] = hs[wave];

  f4_t acc[16];
  bf8_t af[8];

  // ---- lin1: A = dyt1(z row [192]) from global ----
  {
    int r = row0 + col; if (r >= M) r = M - 1;
    const unsigned short* zp = z_bf + (size_t)r * 192;
    float al = d1a[0];
    bf8_t a6[6];
    #pragma unroll
    for (int s = 0; s < 6; ++s) {
      int k0 = s * 32 + quad * 8;
      bf8_t v = *(const bf8_t*)(zp + k0);
      #pragma unroll
      for (int j = 0; j < 8; ++j) {
        float f = bf2f((unsigned short)v[j]);
        f = d1w[k0 + j] * tanhf(al * f) + d1b[k0 + j];
        v[j] = (short)f2bf(f);
      }
      a6[s] = v;
    }
    #pragma unroll
    for (int nt = 0; nt < 16; ++nt) acc[nt] = (f4_t)0.f;
    #pragma unroll
    for (int s = 0; s < 6; ++s) {
      int k0 = s * 32 + quad * 8;
      #pragma unroll
      for (int nt = 0; nt < 16; ++nt) {
        bf8_t b = *(const bf8_t*)(wt1 + (size_t)(nt * 16 + col) * 192 + k0);
        acc[nt] = __builtin_amdgcn_mfma_f32_16x16x32_bf16(a6[s], b, acc[nt], 0, 0, 0);
      }
    }
    #pragma unroll
    for (int nt = 0; nt < 16; ++nt) {
      float bs = b1[nt * 16 + col];
      #pragma unroll
      for (int r4 = 0; r4 < 4; ++r4)
        h[quad * 4 + r4][nt * 16 + col] = f2bf(gelu_f(acc[nt][r4] + bs));
    }
  }

  // ---- lin2: K=256 from LDS ----
  {
    #pragma unroll
    for (int s = 0; s < 8; ++s) af[s] = *(const bf8_t*)&h[col][s * 32 + quad * 8];
    #pragma unroll
    for (int nt = 0; nt < 16; ++nt) acc[nt] = (f4_t)0.f;
    #pragma unroll
    for (int s = 0; s < 8; ++s) {
      int k0 = s * 32 + quad * 8;
      #pragma unroll
      for (int nt = 0; nt < 16; ++nt) {
        bf8_t b = *(const bf8_t*)(wt2 + (size_t)(nt * 16 + col) * 256 + k0);
        acc[nt] = __builtin_amdgcn_mfma_f32_16x16x32_bf16(af[s], b, acc[nt], 0, 0, 0);
      }
    }
    #pragma unroll
    for (int nt = 0; nt < 16; ++nt) {
      float bs = b2[nt * 16 + col];
      #pragma unroll
      for (int r4 = 0; r4 < 4; ++r4)
        h[quad * 4 + r4][nt * 16 + col] = f2bf(gelu_f(acc[nt][r4] + bs));
    }
  }

  // ---- lin3 (K=256,N=64) + dyt2 + residual + row-normalize + adyt1 ----
  {
    #pragma unroll
    for (int s = 0; s < 8; ++s) af[s] = *(const bf8_t*)&h[col][s * 32 + quad * 8];
    f4_t a3[4];
    #pragma unroll
    for (int nt = 0; nt < 4; ++nt) a3[nt] = (f4_t)0.f;
    #pragma unroll
    for (int s = 0; s < 8; ++s) {
      int k0 = s * 32 + quad * 8;
      #pragma unroll
      for (int nt = 0; nt < 4; ++nt) {
        bf8_t b = *(const bf8_t*)(wt3 + (size_t)(nt * 16 + col) * 256 + k0);
        a3[nt] = __builtin_amdgcn_mfma_f32_16x16x32_bf16(af[s], b, a3[nt], 0, 0, 0);
      }
    }
    float al2 = d2a[0], ala = a1a[0];
    float vv[4][4], xr[4][4];
    #pragma unroll
    for (int nt = 0; nt < 4; ++nt) {
      int d = nt * 16 + col;
      float bs = b3[d];
      #pragma unroll
      for (int r4 = 0; r4 < 4; ++r4) {
        int row = row0 + quad * 4 + r4;
        int rc = (row >= M) ? (M - 1) : row;
        float g = gelu_f(a3[nt][r4] + bs);
        float x = x_res[(size_t)rc * 64 + d];
        vv[nt][r4] = d2w[d] * tanhf(al2 * g) + d2b[d] + x;
        xr[nt][r4] = x;
      }
    }
    float sum2[4];
    #pragma unroll
    for (int r4 = 0; r4 < 4; ++r4) {
      float s2 = 0.f;
      #pragma unroll
      for (int nt = 0; nt < 4; ++nt) s2 += vv[nt][r4] * vv[nt][r4];
      s2 += __shfl_xor(s2, 1, 64);
      s2 += __shfl_xor(s2, 2, 64);
      s2 += __shfl_xor(s2, 4, 64);
      s2 += __shfl_xor(s2, 8, 64);
      sum2[r4] = 1.0f / (sqrtf(s2) + 1e-10f);
    }
    #pragma unroll
    for (int nt = 0; nt < 4; ++nt) {
      int d = nt * 16 + col;
      #pragma unroll
      for (int r4 = 0; r4 < 4; ++r4) {
        int row = row0 + quad * 4 + r4;
        float zv = vv[nt][r4] * sum2[r4];
        if (row < M) zn_bf[(size_t)row * 64 + d] = f2bf(zv);
        // dec_in = adyt1([x_res, zn])
        h[quad * 4 + r4][d]      = f2bf(a1w[d] * tanhf(ala * xr[nt][r4]) + a1b[d]);
        h[quad * 4 + r4][64 + d] = f2bf(a1w[64 + d] * tanhf(ala * zv) + a1b[64 + d]);
      }
    }
  }

  // ---- aa1: K=128 from LDS ----
  {
    #pragma unroll
    for (int s = 0; s < 4; ++s) af[s] = *(const bf8_t*)&h[col][s * 32 + quad * 8];
    #pragma unroll
    for (int nt = 0; nt < 16; ++nt) acc[nt] = (f4_t)0.f;
    #pragma unroll
    for (int s = 0; s < 4; ++s) {
      int k0 = s * 32 + quad * 8;
      #pragma unroll
      for (int nt = 0; nt < 16; ++nt) {
        bf8_t b = *(const bf8_t*)(wa1 + (size_t)(nt * 16 + col) * 128 + k0);
        acc[nt] = __builtin_amdgcn_mfma_f32_16x16x32_bf16(af[s], b, acc[nt], 0, 0, 0);
      }
    }
    #pragma unroll
    for (int nt = 0; nt < 16; ++nt) {
      float bs = ba1[nt * 16 + col];
      #pragma unroll
      for (int r4 = 0; r4 < 4; ++r4)
        h[quad * 4 + r4][nt * 16 + col] = f2bf(gelu_f(acc[nt][r4] + bs));
    }
  }

  // ---- aa2, aa3: K=256 from LDS ----
  const unsigned short* ws2[2] = {wa2, wa3};
  const float* bs2[2] = {ba2, ba3};
  for (int layer = 0; layer < 2; ++layer) {
    const unsigned short* w = ws2[layer];
    const float* bb = bs2[layer];
    #pragma unroll
    for (int s = 0; s < 8; ++s) af[s] = *(const bf8_t*)&h[col][s * 32 + quad * 8];
    #pragma unroll
    for (int nt = 0; nt < 16; ++nt) acc[nt] = (f4_t)0.f;
    #pragma unroll
    for (int s = 0; s < 8; ++s) {
      int k0 = s * 32 + quad * 8;
      #pragma unroll
      for (int nt = 0; nt < 16; ++nt) {
        bf8_t b = *(const bf8_t*)(w + (size_t)(nt * 16 + col) * 256 + k0);
        acc[nt] = __builtin_amdgcn_mfma_f32_16x16x32_bf16(af[s], b, acc[nt], 0, 0, 0);
      }
    }
    #pragma unroll
    for (int nt = 0; nt < 16; ++nt) {
      float bsv = bb[nt * 16 + col];
      #pragma unroll
      for (int r4 = 0; r4 < 4; ++r4)
        h[quad * 4 + r4][nt * 16 + col] = f2bf(gelu_f(acc[nt][r4] + bsv));
    }
  }

  // ---- aa4 (adyt2 on A; K=256, N=20 padded 32) + log_softmax ----
  {
    float ala2 = a2a[0];
    #pragma unroll
    for (int s = 0; s < 8; ++s) {
      int k0 = s * 32 + quad * 8;
      bf8_t v = *(const bf8_t*)&h[col][k0];
      #pragma unroll
      for (int j = 0; j < 8; ++j) {
        float f = bf2f((unsigned short)v[j]);
        f = a2w[k0 + j] * tanhf(ala2 * f) + a2b[k0 + j];
        v[j] = (short)f2bf(f);
      }
      af[s] = v;
    }
    f4_t a4[2];
    a4[0] = (f4_t)0.f; a4[1] = (f4_t)0.f;
    #pragma unroll
    for (int s = 0; s < 8; ++s) {
      int k0 = s * 32 + quad * 8;
      #pragma unroll
      for (int nt = 0; nt < 2; ++nt) {
        bf8_t b = *(const bf8_t*)(wa4 + (size_t)(nt * 16 + col) * 256 + k0);
        a4[nt] = __builtin_amdgcn_mfma_f32_16x16x32_bf16(af[s], b, a4[nt], 0, 0, 0);
      }
    }
    // lsm: n = nt*16+col; valid n<20 (nt0 all, nt1 col<4)
    float val[2][4];
    #pragma unroll
    for (int nt = 0; nt < 2; ++nt) {
      int n = nt * 16 + col;
      float bsv = (n < 20) ? ba4[n] : 0.f;
      #pragma unroll
      for (int r4 = 0; r4 < 4; ++r4) val[nt][r4] = a4[nt][r4] + bsv;
    }
    bool v1 = (col < 4);
    #pragma unroll
    for (int r4 = 0; r4 < 4; ++r4) {
      float m = val[0][r4];
      if (v1) m = fmaxf(m, val[1][r4]);
      m = fmaxf(m, __shfl_xor(m, 1, 64));
      m = fmaxf(m, __shfl_xor(m, 2, 64));
      m = fmaxf(m, __shfl_xor(m, 4, 64));
      m = fmaxf(m, __shfl_xor(m, 8, 64));
      float se = expf(val[0][r4] - m) + (v1 ? expf(val[1][r4] - m) : 0.f);
      se += __shfl_xor(se, 1, 64);
      se += __shfl_xor(se, 2, 64);
      se += __shfl_xor(se, 4, 64);
      se += __shfl_xor(se, 8, 64);
      float ls = logf(se) + m;
      int row = row0 + quad * 4 + r4;
      if (row < M) {
        out[(size_t)row * 20 + col] = val[0][r4] - ls;
        if (v1) out[(size_t)row * 20 + 16 + col] = val[1][r4] - ls;
      }
    }
  }
}

// ---------------- fused edge head (prefetching, barrier-free) ----------------
// 16 rows/wave, 64 rows/block-tile, grid-stride with next-tile gather prefetch.
__global__ __launch_bounds__(256) void k_edge(
    const unsigned short* __restrict__ zn_bf,
    const int* __restrict__ ci, const int* __restrict__ cj,
    const unsigned short* __restrict__ w1t, const float* __restrict__ b1,
    const unsigned short* __restrict__ w2t, const float* __restrict__ b2,
    const float* __restrict__ w3, const float* __restrict__ b3,
    float* __restrict__ out, int M) {
  __shared__ unsigned short h1s[4][16][136];
  int lane = threadIdx.x & 63, wave = threadIdx.x >> 6;
  int quad = lane >> 4, col = lane & 15;
  unsigned short (*h1)[136] = h1s[wave];
  int ntiles = (M + 63) >> 6;
  float b3v = b3[0];

  int tile = blockIdx.x;
  bf8_t afrag[4];
  if (tile < ntiles) {
    int r = tile * 64 + wave * 16 + col; if (r >= M) r = M - 1;
    const unsigned short* p0 = zn_bf + (size_t)ci[r] * 64;
    const unsigned short* p1 = zn_bf + (size_t)cj[r] * 64;
    afrag[0] = *(const bf8_t*)(p0 + quad * 8);
    afrag[1] = *(const bf8_t*)(p0 + 32 + quad * 8);
    afrag[2] = *(const bf8_t*)(p1 + quad * 8);
    afrag[3] = *(const bf8_t*)(p1 + 32 + quad * 8);
  }

  for (; tile < ntiles; tile += gridDim.x) {
    // ---- c1 ----
    f4_t acc[8];
    #pragma unroll
    for (int nt = 0; nt < 8; ++nt) acc[nt] = (f4_t)0.f;
    #pragma unroll
    for (int s = 0; s < 4; ++s) {
      int kf = s * 32 + quad * 8;
      #pragma unroll
      for (int nt = 0; nt < 8; ++nt) {
        bf8_t b = *(const bf8_t*)(w1t + (size_t)(nt * 16 + col) * 128 + kf);
        acc[nt] = __builtin_amdgcn_mfma_f32_16x16x32_bf16(afrag[s], b, acc[nt], 0, 0, 0);
      }
    }

    // ---- prefetch next tile's gathers (ages through epilogue+c2) ----
    int nxt = tile + gridDim.x;
    bf8_t nfrag[4];
    bool has_next = (nxt < ntiles);
    if (has_next) {
      int r = nxt * 64 + wave * 16 + col; if (r >= M) r = M - 1;
      const unsigned short* p0 = zn_bf + (size_t)ci[r] * 64;
      const unsigned short* p1 = zn_bf + (size_t)cj[r] * 64;
      nfrag[0] = *(const bf8_t*)(p0 + quad * 8);
      nfrag[1] = *(const bf8_t*)(p0 + 32 + quad * 8);
      nfrag[2] = *(const bf8_t*)(p1 + quad * 8);
      nfrag[3] = *(const bf8_t*)(p1 + 32 + quad * 8);
    }

    // ---- c1 epilogue -> per-wave LDS (no barrier) ----
    #pragma unroll
    for (int nt = 0; nt < 8; ++nt) {
      float bs = b1[nt * 16 + col];
      #pragma unroll
      for (int r4 = 0; r4 < 4; ++r4)
        h1[quad * 4 + r4][nt * 16 + col] = f2bf(gelu_f(acc[nt][r4] + bs));
    }

    // ---- c2 + fused c3 ----
    f4_t a2[8];
    #pragma unroll
    for (int nt = 0; nt < 8; ++nt) a2[nt] = (f4_t)0.f;
    #pragma unroll
    for (int s = 0; s < 4; ++s) {
      int kc = s * 32 + quad * 8;
      bf8_t a0 = *(const bf8_t*)&h1[col][kc];
      #pragma unroll
      for (int nt = 0; nt < 8; ++nt) {
        bf8_t b = *(const bf8_t*)(w2t + (size_t)(nt * 16 + col) * 128 + kc);
        a2[nt] = __builtin_amdgcn_mfma_f32_16x16x32_bf16(a0, b, a2[nt], 0, 0, 0);
      }
    }
    float p[4] = {0.f, 0.f, 0.f, 0.f};
    #pragma unroll
    for (int nt = 0; nt < 8; ++nt) {
      float bs = b2[nt * 16 + col];
      float wv = w3[nt * 16 + col];
      #pragma unroll
      for (int r4 = 0; r4 < 4; ++r4)
        p[r4] += gelu_f(a2[nt][r4] + bs) * wv;
    }
    #pragma unroll
    for (int r4 = 0; r4 < 4; ++r4) {
      float s = p[r4];
      s += __shfl_xor(s, 1, 64);
      s += __shfl_xor(s, 2, 64);
      s += __shfl_xor(s, 4, 64);
      s += __shfl_xor(s, 8, 64);
      if (col == 0) {
        int row = tile * 64 + wave * 16 + quad * 4 + r4;
        if (row < M) out[row] = 1.0f / (1.0f + expf(-(s + b3v)));
      }
    }

    if (has_next) {
      afrag[0] = nfrag[0]; afrag[1] = nfrag[1];
      afrag[2] = nfrag[2]; afrag[3] = nfrag[3];
    }
  }
}

// ---------------- launcher ----------------
extern "C" void kernel_launch(void* const* d_in, const int* in_sizes, int n_in,
                              void* d_out, int out_size, void* d_ws, size_t ws_size,
                              hipStream_t stream) {
  const float* x_res  = (const float*)d_in[0];
  const float* Wl     = (const float*)d_in[1];
  const float* bl     = (const float*)d_in[2];
  const float* Wr     = (const float*)d_in[3];
  const float* gn_w   = (const float*)d_in[4];
  const float* gn_b   = (const float*)d_in[5];
  const float* gn_ms  = (const float*)d_in[6];
  const float* dyt1_w = (const float*)d_in[7];
  const float* dyt1_b = (const float*)d_in[8];
  const float* dyt1_a = (const float*)d_in[9];
  const float* lin1_w = (const float*)d_in[10];
  const float* lin1_b = (const float*)d_in[11];
  const float* lin2_w = (const float*)d_in[12];
  const float* lin2_b = (const float*)d_in[13];
  const float* lin3_w = (const float*)d_in[14];
  const float* lin3_b = (const float*)d_in[15];
  const float* dyt2_w = (const float*)d_in[16];
  const float* dyt2_b = (const float*)d_in[17];
  const float* dyt2_a = (const float*)d_in[18];
  const float* adyt1_w = (const float*)d_in[19];
  const float* adyt1_b = (const float*)d_in[20];
  const float* adyt1_a = (const float*)d_in[21];
  const float* aa1_w  = (const float*)d_in[22];
  const float* aa1_b  = (const float*)d_in[23];
  const float* aa2_w  = (const float*)d_in[24];
  const float* aa2_b  = (const float*)d_in[25];
  const float* aa3_w  = (const float*)d_in[26];
  const float* aa3_b  = (const float*)d_in[27];
  const float* adyt2_w = (const float*)d_in[28];
  const float* adyt2_b = (const float*)d_in[29];
  const float* adyt2_a = (const float*)d_in[30];
  const float* aa4_w  = (const float*)d_in[31];
  const float* aa4_b  = (const float*)d_in[32];
  const float* c1_w   = (const float*)d_in[33];
  const float* c1_b   = (const float*)d_in[34];
  const float* c2_w   = (const float*)d_in[35];
  const float* c2_b   = (const float*)d_in[36];
  const float* c3_w   = (const float*)d_in[37];
  const float* c3_b   = (const float*)d_in[38];
  const int*   edge   = (const int*)d_in[39];
  const int*   contact = (const int*)d_in[40];

  const size_t N = (size_t)Nn;
  const size_t ws_floats = ws_size / 4;

  // ---- persistent region (floats) ----
  float* ws    = (float*)d_ws;
  float* rdeg  = ws;                                  // N
  float* hbuf  = rdeg + N;                            // 64N fp32 (SAGE pre-norm)
  unsigned short* z_bf  = (unsigned short*)(hbuf + 64 * N); // 192N shorts
  unsigned short* zn_bf = z_bf + 192 * N;                   // 64N shorts (xb during GNN)
  float* stats = (float*)(zn_bf + 64 * N);            // 256
  unsigned short* wt_sage = (unsigned short*)(stats + 256); // 3*64*128
  unsigned short* wt_lin1 = wt_sage + 3 * 64 * 128;
  unsigned short* wt_lin2 = wt_lin1 + 256 * 192;
  unsigned short* wt_lin3 = wt_lin2 + 256 * 256;
  unsigned short* wt_aa1  = wt_lin3 + 64 * 256;
  unsigned short* wt_aa2  = wt_aa1 + 256 * 128;
  unsigned short* wt_aa3  = wt_aa2 + 256 * 256;
  unsigned short* wt_aa4  = wt_aa3 + 256 * 256;
  unsigned short* wt_c1   = wt_aa4 + 32 * 256;
  unsigned short* wt_c2   = wt_c1 + 128 * 128;
  unsigned short* wt_end  = wt_c2 + 128 * 128;
  float* pool  = (float*)((((uintptr_t)wt_end + 15) & ~(uintptr_t)15));
  const size_t persist = (size_t)(pool - ws);

  const size_t gnn_need = 32 * N + N + (N + 1) + N + (size_t)Ee + 256;
  if (ws_floats < persist + gnn_need) return;

  unsigned short* agg_bf = (unsigned short*)pool;
  int* cnt     = (int*)(pool + 32 * N);
  int* rowptr  = cnt + N;
  int* cursor  = rowptr + N + 1;
  int* colidx  = cursor + N;
  int* bsum    = colidx + Ee;

  const int* esrc = edge;
  const int* edst = edge + Ee;

  // ---- CSR build ----
  hipMemsetAsync(cnt, 0, N * sizeof(int), stream);
  k_degi<<<(Ee + 255) / 256, 256, 0, stream>>>(edst, cnt, Ee);
  k_rdeg<<<(Nn + 255) / 256, 256, 0, stream>>>(cnt, rdeg, Nn);
  const int nb = (Nn + 1023) / 1024;
  k_scan1<<<nb, 256, 0, stream>>>(cnt, cursor, bsum, Nn);
  k_scan2<<<1, 256, 0, stream>>>(bsum, nb);
  k_scan3<<<(Nn + 255) / 256, 256, 0, stream>>>(cursor, bsum, rowptr, cursor, Nn, Ee);
  k_fill<<<(Ee + 255) / 256, 256, 0, stream>>>(esrc, edst, cursor, colidx, Ee);

  // ---- weight prep ----
  k_wtsage<<<(3 * 64 * 128 + 255) / 256, 256, 0, stream>>>(Wl, Wr, wt_sage);
  k_wt2<<<(256 * 192 + 255) / 256, 256, 0, stream>>>(lin1_w, wt_lin1, 192, 256, 256 * 192);
  k_wt2<<<(256 * 256 + 255) / 256, 256, 0, stream>>>(lin2_w, wt_lin2, 256, 256, 256 * 256);
  k_wt2<<<(64 * 256 + 255) / 256, 256, 0, stream>>>(lin3_w, wt_lin3, 256, 64, 64 * 256);
  k_wt2<<<(256 * 128 + 255) / 256, 256, 0, stream>>>(aa1_w, wt_aa1, 128, 256, 256 * 128);
  k_wt2<<<(256 * 256 + 255) / 256, 256, 0, stream>>>(aa2_w, wt_aa2, 256, 256, 256 * 256);
  k_wt2<<<(256 * 256 + 255) / 256, 256, 0, stream>>>(aa3_w, wt_aa3, 256, 256, 256 * 256);
  k_wt2<<<(32 * 256 + 255) / 256, 256, 0, stream>>>(aa4_w, wt_aa4, 256, 20, 32 * 256);
  k_wt2<<<(128 * 128 + 255) / 256, 256, 0, stream>>>(c1_w, wt_c1, 128, 128, 128 * 128);
  k_wt2<<<(128 * 128 + 255) / 256, 256, 0, stream>>>(c2_w, wt_c2, 128, 128, 128 * 128);

  // xb = bf16(x_res) in zn_bf slot (layer-0 gather input + SAGE A2)
  k_cvt<<<(int)((N * 64 + 255) / 256), 256, 0, stream>>>(x_res, zn_bf, (int)(N * 64));

  // ---- GNN phase ----
  for (int l = 0; l < 3; ++l) {
    const unsigned short* xi = (l == 0) ? zn_bf : (z_bf + (size_t)(l - 1) * 64);
    int ldx = (l == 0) ? 64 : 192;
    hipMemsetAsync(stats, 0, 128 * sizeof(float), stream);
    k_gather<<<(Nn + 3) / 4, 256, 0, stream>>>(xi, ldx, rowptr, colidx, rdeg, agg_bf, Nn);
    mgemm<4><<<dim3((Nn + 127) / 128, 1), 256, 0, stream>>>(
        agg_bf, 64, xi, ldx, 64, 1,
        wt_sage + (size_t)l * 8192, bl + l * 64, hbuf, 64, 0, 1, Nn, 128, 64);
    k_stats<<<1024, 256, 0, stream>>>(hbuf, stats, Nn);
    k_statfin<<<1, 64, 0, stream>>>(stats, gn_ms + l * 64, Nn);
    k_norm<<<(Nn * 64) / 256, 256, 0, stream>>>(hbuf, stats, gn_w + l * 64, gn_b + l * 64,
                                                z_bf + (size_t)l * 64,
                                                (l > 0) ? (z_bf + (size_t)(l - 1) * 64) : nullptr, Nn);
  }

  // ---- fused node pipeline (replaces lin chain + rownorm + annotation head) ----
  k_node<<<(Nn + 63) / 64, 256, 0, stream>>>(
      z_bf, x_res,
      dyt1_w, dyt1_b, dyt1_a, wt_lin1, lin1_b, wt_lin2, lin2_b, wt_lin3, lin3_b,
      dyt2_w, dyt2_b, dyt2_a,
      adyt1_w, adyt1_b, adyt1_a, wt_aa1, aa1_b, wt_aa2, aa2_b, wt_aa3, aa3_b,
      adyt2_w, adyt2_b, adyt2_a, wt_aa4, aa4_b,
      zn_bf, (float*)d_out, Nn);

  // ---- fused edge head ----
  float* eout = (float*)d_out + (size_t)Nn * 20;
  k_edge<<<2048, 256, 0, stream>>>(zn_bf, contact, contact + EPp,
      wt_c1, c1_b, wt_c2, c2_b, c3_w, c3_b, eout, EPp);
}

// Round 6
// 2732.272 us; speedup vs baseline: 1.0425x; 1.0425x over previous
//
#include <hip/hip_runtime.h>
#include <cstdint>
#include <cstddef>

// ---------------- problem constants ----------------
constexpr int Nn  = 200000;
constexpr int Ee  = 1600000;
constexpr int EPp = 1000000;

typedef __attribute__((ext_vector_type(8))) short bf8_t;
typedef __attribute__((ext_vector_type(4))) float f4_t;

__device__ inline unsigned short f2bf(float f) {
  union { float f; unsigned u; } v; v.f = f;
  unsigned r = v.u + 0x7FFFu + ((v.u >> 16) & 1u);
  return (unsigned short)(r >> 16);
}
__device__ inline float bf2f(unsigned short u) {
  union { unsigned u; float f; } v; v.u = ((unsigned)u) << 16;
  return v.f;
}
__device__ inline float gelu_f(float v) {
  return 0.5f * v * (1.0f + erff(v * 0.70710678118654752f));
}

// ---------------- degree / CSR build ----------------

__global__ __launch_bounds__(256) void k_degi(const int* __restrict__ dst,
                                              int* __restrict__ cnt, int E) {
  int i = blockIdx.x * 256 + threadIdx.x;
  if (i < E) atomicAdd(&cnt[dst[i]], 1);
}

__global__ __launch_bounds__(256) void k_rdeg(const int* __restrict__ cnt,
                                              float* __restrict__ rdeg, int n) {
  int i = blockIdx.x * 256 + threadIdx.x;
  if (i < n) rdeg[i] = 1.0f / (float)(cnt[i] > 1 ? cnt[i] : 1);
}

__global__ __launch_bounds__(256) void k_scan1(const int* __restrict__ in,
                                               int* __restrict__ out,
                                               int* __restrict__ bsum, int n) {
  __shared__ int sd[256];
  int t = threadIdx.x;
  int base = blockIdx.x * 1024 + t * 4;
  int v[4]; int ts = 0;
  #pragma unroll
  for (int j = 0; j < 4; ++j) { v[j] = (base + j < n) ? in[base + j] : 0; ts += v[j]; }
  sd[t] = ts; __syncthreads();
  for (int off = 1; off < 256; off <<= 1) {
    int x = (t >= off) ? sd[t - off] : 0;
    __syncthreads();
    sd[t] += x;
    __syncthreads();
  }
  int excl = sd[t] - ts;
  #pragma unroll
  for (int j = 0; j < 4; ++j) { if (base + j < n) out[base + j] = excl; excl += v[j]; }
  if (t == 255) bsum[blockIdx.x] = sd[255];
}

__global__ void k_scan2(int* bsum, int nb) {
  __shared__ int sd[256];
  int t = threadIdx.x;
  int v = (t < nb) ? bsum[t] : 0;
  sd[t] = v; __syncthreads();
  for (int off = 1; off < 256; off <<= 1) {
    int x = (t >= off) ? sd[t - off] : 0;
    __syncthreads();
    sd[t] += x;
    __syncthreads();
  }
  if (t < nb) bsum[t] = sd[t] - v;
}

__global__ __launch_bounds__(256) void k_scan3(const int* __restrict__ part,
                                               const int* __restrict__ bsum,
                                               int* __restrict__ rowptr,
                                               int* __restrict__ cursor,
                                               int n, int total) {
  int i = blockIdx.x * 256 + threadIdx.x;
  if (i == 0) rowptr[n] = total;
  if (i < n) { int v = part[i] + bsum[i >> 10]; rowptr[i] = v; cursor[i] = v; }
}

__global__ __launch_bounds__(256) void k_fill(const int* __restrict__ src,
                                              const int* __restrict__ dst,
                                              int* __restrict__ cursor,
                                              int* __restrict__ colidx, int E) {
  int e = blockIdx.x * 256 + threadIdx.x;
  if (e >= E) return;
  int pos = atomicAdd(&cursor[dst[e]], 1);
  colidx[pos] = src[e];
}

// gather-mean over bf16 features: one wave per node, 8 groups of 8 lanes
__global__ __launch_bounds__(256) void k_gather(const unsigned short* __restrict__ x, int ldx,
                                                const int* __restrict__ rowptr,
                                                const int* __restrict__ colidx,
                                                const float* __restrict__ rdeg,
                                                unsigned short* __restrict__ agg, int n) {
  int wave = threadIdx.x >> 6, lane = threadIdx.x & 63;
  int node = blockIdx.x * 4 + wave;
  if (node >= n) return;
  int grp = lane >> 3, c = (lane & 7) * 8;
  int r0 = rowptr[node], r1 = rowptr[node + 1];
  float s[8] = {0.f, 0.f, 0.f, 0.f, 0.f, 0.f, 0.f, 0.f};
  for (int j = r0 + grp; j < r1; j += 8) {
    bf8_t v = *(const bf8_t*)(x + (size_t)colidx[j] * ldx + c);
    #pragma unroll
    for (int jj = 0; jj < 8; ++jj) s[jj] += bf2f((unsigned short)v[jj]);
  }
  #pragma unroll
  for (int jj = 0; jj < 8; ++jj) {
    s[jj] += __shfl_xor(s[jj], 8, 64);
    s[jj] += __shfl_xor(s[jj], 16, 64);
    s[jj] += __shfl_xor(s[jj], 32, 64);
  }
  if (grp == 0) {
    float r = rdeg[node];
    bf8_t o;
    #pragma unroll
    for (int jj = 0; jj < 8; ++jj) o[jj] = (short)f2bf(s[jj] * r);
    *(bf8_t*)(agg + (size_t)node * 64 + c) = o;
  }
}

// ---------------- misc small kernels ----------------

__global__ __launch_bounds__(256) void k_cvt(const float* __restrict__ in,
                                             unsigned short* __restrict__ out, int n) {
  int i = blockIdx.x * 256 + threadIdx.x;
  if (i < n) out[i] = f2bf(in[i]);
}

// transpose + cvt weights: W[K][N] fp32 -> Wt[Npad][K] bf16 (zero-fill n>=N)
__global__ __launch_bounds__(256) void k_wt2(const float* __restrict__ W,
                                             unsigned short* __restrict__ Wt,
                                             int K, int N, int total) {
  int i = blockIdx.x * 256 + threadIdx.x;
  if (i >= total) return;
  int n = i / K, k = i - n * K;
  float v = (n < N) ? W[(size_t)k * N + n] : 0.f;
  Wt[i] = f2bf(v);
}

// SAGE weights: Wt[l][n][k] = (k<64 ? Wl[l][k][n] : Wr[l][k-64][n])
__global__ __launch_bounds__(256) void k_wtsage(const float* __restrict__ Wl,
                                                const float* __restrict__ Wr,
                                                unsigned short* __restrict__ Wt) {
  int i = blockIdx.x * 256 + threadIdx.x;
  if (i >= 3 * 64 * 128) return;
  int l = i >> 13, r = i & 8191, n = r >> 7, k = r & 127;
  float v = (k < 64) ? Wl[l * 4096 + k * 64 + n] : Wr[l * 4096 + (k - 64) * 64 + n];
  Wt[i] = f2bf(v);
}

__global__ __launch_bounds__(256) void k_stats(const float* __restrict__ h,
                                               float* __restrict__ stats, int n) {
  int lane = threadIdx.x & 63, grp = threadIdx.x >> 6;
  float s = 0.f, s2 = 0.f;
  for (int r = blockIdx.x * 4 + grp; r < n; r += gridDim.x * 4) {
    float v = h[(size_t)r * 64 + lane];
    s += v; s2 += v * v;
  }
  __shared__ float l1[4][64], l2[4][64];
  l1[grp][lane] = s; l2[grp][lane] = s2;
  __syncthreads();
  if (grp == 0) {
    s  = l1[0][lane] + l1[1][lane] + l1[2][lane] + l1[3][lane];
    s2 = l2[0][lane] + l2[1][lane] + l2[2][lane] + l2[3][lane];
    atomicAdd(&stats[lane], s);
    atomicAdd(&stats[64 + lane], s2);
  }
}

__global__ void k_statfin(float* stats, const float* __restrict__ ms_, int n) {
  int d = threadIdx.x;
  if (d < 64) {
    float invn = 1.0f / (float)n;
    float m  = stats[d] * invn;
    float e2 = stats[64 + d] * invn;
    float ms = ms_[d];
    float var = e2 - (2.0f * ms - ms * ms) * m * m;
    stats[128 + d] = ms * m;
    stats[192 + d] = rsqrtf(var + 1e-5f);
  }
}

// graph_norm apply + residual; write bf16 z column (row stride 192 shorts)
__global__ __launch_bounds__(256) void k_norm(const float* __restrict__ h,
                                              const float* __restrict__ stats,
                                              const float* __restrict__ w,
                                              const float* __restrict__ b,
                                              unsigned short* __restrict__ zcol,
                                              const unsigned short* __restrict__ prev, int n) {
  int i = blockIdx.x * 256 + threadIdx.x;
  if (i >= n * 64) return;
  int r = i >> 6, d = i & 63;
  float v = (h[i] - stats[128 + d]) * stats[192 + d] * w[d] + b[d];
  if (prev) v += bf2f(prev[(size_t)r * 192 + d]);
  zcol[(size_t)r * 192 + d] = f2bf(v);
}

// ---------------- generic bf16 MFMA GEMM (barrier-free, for SAGE) ----------------
template <int NT>
__global__ __launch_bounds__(256) void mgemm(
    const void* __restrict__ A1, int lda1,
    const void* __restrict__ A2, int lda2, int K1, int a_bf16,
    const unsigned short* __restrict__ Wt,
    const float* __restrict__ bias,
    void* __restrict__ Cout, int ldc, int c_bf16, int act,
    int M, int K, int N) {
  int lane = threadIdx.x & 63, wave = threadIdx.x >> 6;
  int quad = lane >> 4, col = lane & 15;
  int row0 = blockIdx.x * 128 + wave * 32;
  int n_base = blockIdx.y * NT * 16;

  f4_t acc[2][NT];
  #pragma unroll
  for (int mt = 0; mt < 2; ++mt)
    #pragma unroll
    for (int nt = 0; nt < NT; ++nt) acc[mt][nt] = (f4_t)0.f;

  int gm[2];
  gm[0] = row0 + col;      if (gm[0] >= M) gm[0] = M - 1;
  gm[1] = row0 + 16 + col; if (gm[1] >= M) gm[1] = M - 1;

  for (int kc0 = 0; kc0 < K; kc0 += 32) {
    int kc = kc0 + quad * 8;
    bf8_t a[2];
    #pragma unroll
    for (int mt = 0; mt < 2; ++mt) {
      const void* src; size_t off;
      if (kc < K1) { src = A1; off = (size_t)gm[mt] * lda1 + kc; }
      else         { src = A2; off = (size_t)gm[mt] * lda2 + kc - K1; }
      if (a_bf16) {
        a[mt] = *(const bf8_t*)((const unsigned short*)src + off);
      } else {
        const float* p = (const float*)src + off;
        float4 f0 = *(const float4*)p;
        float4 f1 = *(const float4*)(p + 4);
        float ff[8] = {f0.x, f0.y, f0.z, f0.w, f1.x, f1.y, f1.z, f1.w};
        #pragma unroll
        for (int j = 0; j < 8; ++j) a[mt][j] = (short)f2bf(ff[j]);
      }
    }
    #pragma unroll
    for (int nt = 0; nt < NT; ++nt) {
      bf8_t b = *(const bf8_t*)(Wt + (size_t)(n_base + nt * 16 + col) * K + kc);
      acc[0][nt] = __builtin_amdgcn_mfma_f32_16x16x32_bf16(a[0], b, acc[0][nt], 0, 0, 0);
      acc[1][nt] = __builtin_amdgcn_mfma_f32_16x16x32_bf16(a[1], b, acc[1][nt], 0, 0, 0);
    }
  }

  #pragma unroll
  for (int nt = 0; nt < NT; ++nt) {
    int n = n_base + nt * 16 + col;
    float bs = (bias && n < N) ? bias[n] : 0.f;
    #pragma unroll
    for (int mt = 0; mt < 2; ++mt)
      #pragma unroll
      for (int r = 0; r < 4; ++r) {
        int row = row0 + mt * 16 + quad * 4 + r;
        if (row >= M || n >= N) continue;
        float v = acc[mt][nt][r] + bs;
        if (act) v = gelu_f(v);
        if (c_bf16) ((unsigned short*)Cout)[(size_t)row * ldc + n] = f2bf(v);
        else        ((float*)Cout)[(size_t)row * ldc + n] = v;
      }
  }
}

// ---------------- block-cooperative fused node pipeline ----------------
// Block = 256 thr = 4 waves = 64 rows. Activations ping-pong in LDS (A_,B_).
// Per GEMM layer, wave w computes output cols n in [64w, 64w+64) for ALL 64
// rows (4 m-tiles x 4 n-tiles) -> weights read once per block.
__device__ inline void node_gemm(const unsigned short (*src)[264],
                                 unsigned short (*dst)[264],
                                 const unsigned short* __restrict__ W,
                                 const float* __restrict__ bias, int K,
                                 int wave, int quad, int col,
                                 const float* __restrict__ a2w,
                                 const float* __restrict__ a2b, float ala2) {
  f4_t acc[4][4];
  #pragma unroll
  for (int mt = 0; mt < 4; ++mt)
    #pragma unroll
    for (int nt = 0; nt < 4; ++nt) acc[mt][nt] = (f4_t)0.f;
  int ks = K >> 5;
  for (int s = 0; s < ks; ++s) {
    int k0 = s * 32 + quad * 8;
    bf8_t am[4];
    #pragma unroll
    for (int mt = 0; mt < 4; ++mt)
      am[mt] = *(const bf8_t*)&src[mt * 16 + col][k0];
    #pragma unroll
    for (int nt = 0; nt < 4; ++nt) {
      bf8_t b = *(const bf8_t*)(W + (size_t)(wave * 64 + nt * 16 + col) * K + k0);
      #pragma unroll
      for (int mt = 0; mt < 4; ++mt)
        acc[mt][nt] = __builtin_amdgcn_mfma_f32_16x16x32_bf16(am[mt], b, acc[mt][nt], 0, 0, 0);
    }
  }
  #pragma unroll
  for (int nt = 0; nt < 4; ++nt) {
    int n = wave * 64 + nt * 16 + col;
    float bs = bias[n];
    #pragma unroll
    for (int mt = 0; mt < 4; ++mt)
      #pragma unroll
      for (int r4 = 0; r4 < 4; ++r4) {
        float v = gelu_f(acc[mt][nt][r4] + bs);
        if (a2w) v = a2w[n] * tanhf(ala2 * v) + a2b[n];
        dst[mt * 16 + quad * 4 + r4][n] = f2bf(v);
      }
  }
  __syncthreads();
}

__global__ __launch_bounds__(256) void k_node(
    const unsigned short* __restrict__ z_bf,
    const float* __restrict__ x_res,
    const float* __restrict__ d1w, const float* __restrict__ d1b, const float* __restrict__ d1a,
    const unsigned short* __restrict__ wt1, const float* __restrict__ b1,
    const unsigned short* __restrict__ wt2, const float* __restrict__ b2,
    const unsigned short* __restrict__ wt3, const float* __restrict__ b3,
    const float* __restrict__ d2w, const float* __restrict__ d2b, const float* __restrict__ d2a,
    const float* __restrict__ a1w, const float* __restrict__ a1b, const float* __restrict__ a1a,
    const unsigned short* __restrict__ wa1, const float* __restrict__ ba1,
    const unsigned short* __restrict__ wa2, const float* __restrict__ ba2,
    const unsigned short* __restrict__ wa3, const float* __restrict__ ba3,
    const float* __restrict__ a2w, const float* __restrict__ a2b, const float* __restrict__ a2a,
    const unsigned short* __restrict__ wa4, const float* __restrict__ ba4,
    unsigned short* __restrict__ zn_bf,
    float* __restrict__ out, int M) {
  __shared__ unsigned short A_[64][264];
  __shared__ unsigned short B_[64][264];
  int t = threadIdx.x;
  int lane = t & 63, wave = t >> 6;
  int quad = lane >> 4, col = lane & 15;
  int row0 = blockIdx.x * 64;

  // ---- stage A_ = dyt1(z rows) ----
  {
    int row = t >> 2, part = t & 3;
    int gr = row0 + row; if (gr >= M) gr = M - 1;
    const unsigned short* zp = z_bf + (size_t)gr * 192 + part * 48;
    float al = d1a[0];
    #pragma unroll
    for (int j = 0; j < 6; ++j) {
      bf8_t v = *(const bf8_t*)(zp + j * 8);
      int k0 = part * 48 + j * 8;
      #pragma unroll
      for (int jj = 0; jj < 8; ++jj) {
        float f = bf2f((unsigned short)v[jj]);
        v[jj] = (short)f2bf(d1w[k0 + jj] * tanhf(al * f) + d1b[k0 + jj]);
      }
      *(bf8_t*)&A_[row][k0] = v;
    }
  }
  __syncthreads();

  // ---- lin1 (K=192): A_ -> B_ ----
  node_gemm(A_, B_, wt1, b1, 192, wave, quad, col, nullptr, nullptr, 0.f);
  // ---- lin2 (K=256): B_ -> A_ ----
  node_gemm(B_, A_, wt2, b2, 256, wave, quad, col, nullptr, nullptr, 0.f);

  // ---- lin3 (K=256, N=64; wave w owns n-tile w) + dyt2 + resid + rownorm + adyt1 ----
  {
    f4_t a3[4];
    #pragma unroll
    for (int mt = 0; mt < 4; ++mt) a3[mt] = (f4_t)0.f;
    for (int s = 0; s < 8; ++s) {
      int k0 = s * 32 + quad * 8;
      bf8_t b = *(const bf8_t*)(wt3 + (size_t)(wave * 16 + col) * 256 + k0);
      #pragma unroll
      for (int mt = 0; mt < 4; ++mt) {
        bf8_t am = *(const bf8_t*)&A_[mt * 16 + col][k0];
        a3[mt] = __builtin_amdgcn_mfma_f32_16x16x32_bf16(am, b, a3[mt], 0, 0, 0);
      }
    }
    // vv (fp32) into B_'s storage (B_ fully consumed by lin2; barrier below
    // also orders these writes vs. remaining A_ reads by other waves)
    float* fb = (float*)B_;              // [64][66]
    float al2 = d2a[0];
    int n = wave * 16 + col;
    float bsn = b3[n];
    __syncthreads();                     // all lin3 reads of A_/B_ complete
    #pragma unroll
    for (int mt = 0; mt < 4; ++mt)
      #pragma unroll
      for (int r4 = 0; r4 < 4; ++r4) {
        int row = mt * 16 + quad * 4 + r4;
        int gr = row0 + row; if (gr >= M) gr = M - 1;
        float g = gelu_f(a3[mt][r4] + bsn);
        float x = x_res[(size_t)gr * 64 + n];
        fb[row * 66 + n] = d2w[n] * tanhf(al2 * g) + d2b[n] + x;
      }
    __syncthreads();
    // row-wise sum of squares: thread (row = t>>2, q = t&3) sums 16 cols
    int row = t >> 2, q = t & 3;
    float s2 = 0.f;
    #pragma unroll
    for (int c16 = 0; c16 < 16; ++c16) {
      float v = fb[row * 66 + q * 16 + c16];
      s2 += v * v;
    }
    float* fp = fb + 64 * 66;            // [64][4] partials
    fp[row * 4 + q] = s2;
    __syncthreads();
    float* fi = fp + 256;                // [64] inv norms
    if (t < 64)
      fi[t] = 1.0f / (sqrtf(fp[t * 4] + fp[t * 4 + 1] + fp[t * 4 + 2] + fp[t * 4 + 3]) + 1e-10f);
    __syncthreads();
    // build dec_in = adyt1([x_res, zn]) into A_; write zn_bf
    float ala = a1a[0];
    float inv = fi[row];
    int gr = row0 + row;
    int grc = (gr >= M) ? (M - 1) : gr;
    #pragma unroll
    for (int c16 = 0; c16 < 16; ++c16) {
      int c = q * 16 + c16;
      float zv = fb[row * 66 + c] * inv;
      if (gr < M) zn_bf[(size_t)gr * 64 + c] = f2bf(zv);
      A_[row][64 + c] = f2bf(a1w[64 + c] * tanhf(ala * zv) + a1b[64 + c]);
      float x = x_res[(size_t)grc * 64 + c];
      A_[row][c] = f2bf(a1w[c] * tanhf(ala * x) + a1b[c]);
    }
    __syncthreads();
  }

  // ---- aa1 (K=128): A_ -> B_ ----
  node_gemm(A_, B_, wa1, ba1, 128, wave, quad, col, nullptr, nullptr, 0.f);
  // ---- aa2 (K=256): B_ -> A_ ----
  node_gemm(B_, A_, wa2, ba2, 256, wave, quad, col, nullptr, nullptr, 0.f);
  // ---- aa3 (K=256) + adyt2 epilogue: A_ -> B_ ----
  node_gemm(A_, B_, wa3, ba3, 256, wave, quad, col, a2w, a2b, a2a[0]);

  // ---- aa4 (K=256, N=20 padded 32; wave w owns m-tile w) + log_softmax ----
  {
    f4_t a4[2];
    a4[0] = (f4_t)0.f; a4[1] = (f4_t)0.f;
    for (int s = 0; s < 8; ++s) {
      int k0 = s * 32 + quad * 8;
      bf8_t am = *(const bf8_t*)&B_[wave * 16 + col][k0];
      #pragma unroll
      for (int nt = 0; nt < 2; ++nt) {
        bf8_t b = *(const bf8_t*)(wa4 + (size_t)(nt * 16 + col) * 256 + k0);
        a4[nt] = __builtin_amdgcn_mfma_f32_16x16x32_bf16(am, b, a4[nt], 0, 0, 0);
      }
    }
    float val[2][4];
    #pragma unroll
    for (int nt = 0; nt < 2; ++nt) {
      int n = nt * 16 + col;
      float bsv = (n < 20) ? ba4[n] : 0.f;
      #pragma unroll
      for (int r4 = 0; r4 < 4; ++r4) val[nt][r4] = a4[nt][r4] + bsv;
    }
    bool v1 = (col < 4);
    #pragma unroll
    for (int r4 = 0; r4 < 4; ++r4) {
      float m = val[0][r4];
      if (v1) m = fmaxf(m, val[1][r4]);
      m = fmaxf(m, __shfl_xor(m, 1, 64));
      m = fmaxf(m, __shfl_xor(m, 2, 64));
      m = fmaxf(m, __shfl_xor(m, 4, 64));
      m = fmaxf(m, __shfl_xor(m, 8, 64));
      float se = expf(val[0][r4] - m) + (v1 ? expf(val[1][r4] - m) : 0.f);
      se += __shfl_xor(se, 1, 64);
      se += __shfl_xor(se, 2, 64);
      se += __shfl_xor(se, 4, 64);
      se += __shfl_xor(se, 8, 64);
      float ls = logf(se) + m;
      int row = row0 + wave * 16 + quad * 4 + r4;
      if (row < M) {
        out[(size_t)row * 20 + col] = val[0][r4] - ls;
        if (v1) out[(size_t)row * 20 + 16 + col] = val[1][r4] - ls;
      }
    }
  }
}

// ---------------- fused edge head (prefetching, barrier-free) ----------------
__global__ __launch_bounds__(256) void k_edge(
    const unsigned short* __restrict__ zn_bf,
    const int* __restrict__ ci, const int* __restrict__ cj,
    const unsigned short* __restrict__ w1t, const float* __restrict__ b1,
    const unsigned short* __restrict__ w2t, const float* __restrict__ b2,
    const float* __restrict__ w3, const float* __restrict__ b3,
    float* __restrict__ out, int M) {
  __shared__ unsigned short h1s[4][16][136];
  int lane = threadIdx.x & 63, wave = threadIdx.x >> 6;
  int quad = lane >> 4, col = lane & 15;
  unsigned short (*h1)[136] = h1s[wave];
  int ntiles = (M + 63) >> 6;
  float b3v = b3[0];

  int tile = blockIdx.x;
  bf8_t afrag[4];
  if (tile < ntiles) {
    int r = tile * 64 + wave * 16 + col; if (r >= M) r = M - 1;
    const unsigned short* p0 = zn_bf + (size_t)ci[r] * 64;
    const unsigned short* p1 = zn_bf + (size_t)cj[r] * 64;
    afrag[0] = *(const bf8_t*)(p0 + quad * 8);
    afrag[1] = *(const bf8_t*)(p0 + 32 + quad * 8);
    afrag[2] = *(const bf8_t*)(p1 + quad * 8);
    afrag[3] = *(const bf8_t*)(p1 + 32 + quad * 8);
  }

  for (; tile < ntiles; tile += gridDim.x) {
    f4_t acc[8];
    #pragma unroll
    for (int nt = 0; nt < 8; ++nt) acc[nt] = (f4_t)0.f;
    #pragma unroll
    for (int s = 0; s < 4; ++s) {
      int kf = s * 32 + quad * 8;
      #pragma unroll
      for (int nt = 0; nt < 8; ++nt) {
        bf8_t b = *(const bf8_t*)(w1t + (size_t)(nt * 16 + col) * 128 + kf);
        acc[nt] = __builtin_amdgcn_mfma_f32_16x16x32_bf16(afrag[s], b, acc[nt], 0, 0, 0);
      }
    }

    int nxt = tile + gridDim.x;
    bf8_t nfrag[4];
    bool has_next = (nxt < ntiles);
    if (has_next) {
      int r = nxt * 64 + wave * 16 + col; if (r >= M) r = M - 1;
      const unsigned short* p0 = zn_bf + (size_t)ci[r] * 64;
      const unsigned short* p1 = zn_bf + (size_t)cj[r] * 64;
      nfrag[0] = *(const bf8_t*)(p0 + quad * 8);
      nfrag[1] = *(const bf8_t*)(p0 + 32 + quad * 8);
      nfrag[2] = *(const bf8_t*)(p1 + quad * 8);
      nfrag[3] = *(const bf8_t*)(p1 + 32 + quad * 8);
    }

    #pragma unroll
    for (int nt = 0; nt < 8; ++nt) {
      float bs = b1[nt * 16 + col];
      #pragma unroll
      for (int r4 = 0; r4 < 4; ++r4)
        h1[quad * 4 + r4][nt * 16 + col] = f2bf(gelu_f(acc[nt][r4] + bs));
    }

    f4_t a2[8];
    #pragma unroll
    for (int nt = 0; nt < 8; ++nt) a2[nt] = (f4_t)0.f;
    #pragma unroll
    for (int s = 0; s < 4; ++s) {
      int kc = s * 32 + quad * 8;
      bf8_t a0 = *(const bf8_t*)&h1[col][kc];
      #pragma unroll
      for (int nt = 0; nt < 8; ++nt) {
        bf8_t b = *(const bf8_t*)(w2t + (size_t)(nt * 16 + col) * 128 + kc);
        a2[nt] = __builtin_amdgcn_mfma_f32_16x16x32_bf16(a0, b, a2[nt], 0, 0, 0);
      }
    }
    float p[4] = {0.f, 0.f, 0.f, 0.f};
    #pragma unroll
    for (int nt = 0; nt < 8; ++nt) {
      float bs = b2[nt * 16 + col];
      float wv = w3[nt * 16 + col];
      #pragma unroll
      for (int r4 = 0; r4 < 4; ++r4)
        p[r4] += gelu_f(a2[nt][r4] + bs) * wv;
    }
    #pragma unroll
    for (int r4 = 0; r4 < 4; ++r4) {
      float s = p[r4];
      s += __shfl_xor(s, 1, 64);
      s += __shfl_xor(s, 2, 64);
      s += __shfl_xor(s, 4, 64);
      s += __shfl_xor(s, 8, 64);
      if (col == 0) {
        int row = tile * 64 + wave * 16 + quad * 4 + r4;
        if (row < M) out[row] = 1.0f / (1.0f + expf(-(s + b3v)));
      }
    }

    if (has_next) {
      afrag[0] = nfrag[0]; afrag[1] = nfrag[1];
      afrag[2] = nfrag[2]; afrag[3] = nfrag[3];
    }
  }
}

// ---------------- launcher ----------------
extern "C" void kernel_launch(void* const* d_in, const int* in_sizes, int n_in,
                              void* d_out, int out_size, void* d_ws, size_t ws_size,
                              hipStream_t stream) {
  const float* x_res  = (const float*)d_in[0];
  const float* Wl     = (const float*)d_in[1];
  const float* bl     = (const float*)d_in[2];
  const float* Wr     = (const float*)d_in[3];
  const float* gn_w   = (const float*)d_in[4];
  const float* gn_b   = (const float*)d_in[5];
  const float* gn_ms  = (const float*)d_in[6];
  const float* dyt1_w = (const float*)d_in[7];
  const float* dyt1_b = (const float*)d_in[8];
  const float* dyt1_a = (const float*)d_in[9];
  const float* lin1_w = (const float*)d_in[10];
  const float* lin1_b = (const float*)d_in[11];
  const float* lin2_w = (const float*)d_in[12];
  const float* lin2_b = (const float*)d_in[13];
  const float* lin3_w = (const float*)d_in[14];
  const float* lin3_b = (const float*)d_in[15];
  const float* dyt2_w = (const float*)d_in[16];
  const float* dyt2_b = (const float*)d_in[17];
  const float* dyt2_a = (const float*)d_in[18];
  const float* adyt1_w = (const float*)d_in[19];
  const float* adyt1_b = (const float*)d_in[20];
  const float* adyt1_a = (const float*)d_in[21];
  const float* aa1_w  = (const float*)d_in[22];
  const float* aa1_b  = (const float*)d_in[23];
  const float* aa2_w  = (const float*)d_in[24];
  const float* aa2_b  = (const float*)d_in[25];
  const float* aa3_w  = (const float*)d_in[26];
  const float* aa3_b  = (const float*)d_in[27];
  const float* adyt2_w = (const float*)d_in[28];
  const float* adyt2_b = (const float*)d_in[29];
  const float* adyt2_a = (const float*)d_in[30];
  const float* aa4_w  = (const float*)d_in[31];
  const float* aa4_b  = (const float*)d_in[32];
  const float* c1_w   = (const float*)d_in[33];
  const float* c1_b   = (const float*)d_in[34];
  const float* c2_w   = (const float*)d_in[35];
  const float* c2_b   = (const float*)d_in[36];
  const float* c3_w   = (const float*)d_in[37];
  const float* c3_b   = (const float*)d_in[38];
  const int*   edge   = (const int*)d_in[39];
  const int*   contact = (const int*)d_in[40];

  const size_t N = (size_t)Nn;
  const size_t ws_floats = ws_size / 4;

  // ---- persistent region (floats) ----
  float* ws    = (float*)d_ws;
  float* rdeg  = ws;                                  // N
  float* hbuf  = rdeg + N;                            // 64N fp32 (SAGE pre-norm)
  unsigned short* z_bf  = (unsigned short*)(hbuf + 64 * N); // 192N shorts
  unsigned short* zn_bf = z_bf + 192 * N;                   // 64N shorts (xb during GNN)
  float* stats = (float*)(zn_bf + 64 * N);            // 256
  unsigned short* wt_sage = (unsigned short*)(stats + 256); // 3*64*128
  unsigned short* wt_lin1 = wt_sage + 3 * 64 * 128;
  unsigned short* wt_lin2 = wt_lin1 + 256 * 192;
  unsigned short* wt_lin3 = wt_lin2 + 256 * 256;
  unsigned short* wt_aa1  = wt_lin3 + 64 * 256;
  unsigned short* wt_aa2  = wt_aa1 + 256 * 128;
  unsigned short* wt_aa3  = wt_aa2 + 256 * 256;
  unsigned short* wt_aa4  = wt_aa3 + 256 * 256;
  unsigned short* wt_c1   = wt_aa4 + 32 * 256;
  unsigned short* wt_c2   = wt_c1 + 128 * 128;
  unsigned short* wt_end  = wt_c2 + 128 * 128;
  float* pool  = (float*)((((uintptr_t)wt_end + 15) & ~(uintptr_t)15));
  const size_t persist = (size_t)(pool - ws);

  const size_t gnn_need = 32 * N + N + (N + 1) + N + (size_t)Ee + 256;
  if (ws_floats < persist + gnn_need) return;

  unsigned short* agg_bf = (unsigned short*)pool;
  int* cnt     = (int*)(pool + 32 * N);
  int* rowptr  = cnt + N;
  int* cursor  = rowptr + N + 1;
  int* colidx  = cursor + N;
  int* bsum    = colidx + Ee;

  const int* esrc = edge;
  const int* edst = edge + Ee;

  // ---- CSR build ----
  hipMemsetAsync(cnt, 0, N * sizeof(int), stream);
  k_degi<<<(Ee + 255) / 256, 256, 0, stream>>>(edst, cnt, Ee);
  k_rdeg<<<(Nn + 255) / 256, 256, 0, stream>>>(cnt, rdeg, Nn);
  const int nb = (Nn + 1023) / 1024;
  k_scan1<<<nb, 256, 0, stream>>>(cnt, cursor, bsum, Nn);
  k_scan2<<<1, 256, 0, stream>>>(bsum, nb);
  k_scan3<<<(Nn + 255) / 256, 256, 0, stream>>>(cursor, bsum, rowptr, cursor, Nn, Ee);
  k_fill<<<(Ee + 255) / 256, 256, 0, stream>>>(esrc, edst, cursor, colidx, Ee);

  // ---- weight prep ----
  k_wtsage<<<(3 * 64 * 128 + 255) / 256, 256, 0, stream>>>(Wl, Wr, wt_sage);
  k_wt2<<<(256 * 192 + 255) / 256, 256, 0, stream>>>(lin1_w, wt_lin1, 192, 256, 256 * 192);
  k_wt2<<<(256 * 256 + 255) / 256, 256, 0, stream>>>(lin2_w, wt_lin2, 256, 256, 256 * 256);
  k_wt2<<<(64 * 256 + 255) / 256, 256, 0, stream>>>(lin3_w, wt_lin3, 256, 64, 64 * 256);
  k_wt2<<<(256 * 128 + 255) / 256, 256, 0, stream>>>(aa1_w, wt_aa1, 128, 256, 256 * 128);
  k_wt2<<<(256 * 256 + 255) / 256, 256, 0, stream>>>(aa2_w, wt_aa2, 256, 256, 256 * 256);
  k_wt2<<<(256 * 256 + 255) / 256, 256, 0, stream>>>(aa3_w, wt_aa3, 256, 256, 256 * 256);
  k_wt2<<<(32 * 256 + 255) / 256, 256, 0, stream>>>(aa4_w, wt_aa4, 256, 20, 32 * 256);
  k_wt2<<<(128 * 128 + 255) / 256, 256, 0, stream>>>(c1_w, wt_c1, 128, 128, 128 * 128);
  k_wt2<<<(128 * 128 + 255) / 256, 256, 0, stream>>>(c2_w, wt_c2, 128, 128, 128 * 128);

  // xb = bf16(x_res) in zn_bf slot (layer-0 gather input + SAGE A2)
  k_cvt<<<(int)((N * 64 + 255) / 256), 256, 0, stream>>>(x_res, zn_bf, (int)(N * 64));

  // ---- GNN phase ----
  for (int l = 0; l < 3; ++l) {
    const unsigned short* xi = (l == 0) ? zn_bf : (z_bf + (size_t)(l - 1) * 64);
    int ldx = (l == 0) ? 64 : 192;
    hipMemsetAsync(stats, 0, 128 * sizeof(float), stream);
    k_gather<<<(Nn + 3) / 4, 256, 0, stream>>>(xi, ldx, rowptr, colidx, rdeg, agg_bf, Nn);
    mgemm<4><<<dim3((Nn + 127) / 128, 1), 256, 0, stream>>>(
        agg_bf, 64, xi, ldx, 64, 1,
        wt_sage + (size_t)l * 8192, bl + l * 64, hbuf, 64, 0, 1, Nn, 128, 64);
    k_stats<<<1024, 256, 0, stream>>>(hbuf, stats, Nn);
    k_statfin<<<1, 64, 0, stream>>>(stats, gn_ms + l * 64, Nn);
    k_norm<<<(Nn * 64) / 256, 256, 0, stream>>>(hbuf, stats, gn_w + l * 64, gn_b + l * 64,
                                                z_bf + (size_t)l * 64,
                                                (l > 0) ? (z_bf + (size_t)(l - 1) * 64) : nullptr, Nn);
  }

  // ---- block-cooperative fused node pipeline ----
  k_node<<<(Nn + 63) / 64, 256, 0, stream>>>(
      z_bf, x_res,
      dyt1_w, dyt1_b, dyt1_a, wt_lin1, lin1_b, wt_lin2, lin2_b, wt_lin3, lin3_b,
      dyt2_w, dyt2_b, dyt2_a,
      adyt1_w, adyt1_b, adyt1_a, wt_aa1, aa1_b, wt_aa2, aa2_b, wt_aa3, aa3_b,
      adyt2_w, adyt2_b, adyt2_a, wt_aa4, aa4_b,
      zn_bf, (float*)d_out, Nn);

  // ---- fused edge head ----
  float* eout = (float*)d_out + (size_t)Nn * 20;
  k_edge<<<2048, 256, 0, stream>>>(zn_bf, contact, contact + EPp,
      wt_c1, c1_b, wt_c2, c2_b, c3_w, c3_b, eout, EPp);
}

// Round 7
// 1984.472 us; speedup vs baseline: 1.4353x; 1.3768x over previous
//
#include <hip/hip_runtime.h>
#include <cstdint>
#include <cstddef>

// ---------------- problem constants ----------------
constexpr int Nn  = 200000;
constexpr int Ee  = 1600000;
constexpr int EPp = 1000000;

typedef __attribute__((ext_vector_type(8))) short bf8_t;
typedef __attribute__((ext_vector_type(4))) float f4_t;

__device__ inline unsigned short f2bf(float f) {
  union { float f; unsigned u; } v; v.f = f;
  unsigned r = v.u + 0x7FFFu + ((v.u >> 16) & 1u);
  return (unsigned short)(r >> 16);
}
__device__ inline float bf2f(unsigned short u) {
  union { unsigned u; float f; } v; v.u = ((unsigned)u) << 16;
  return v.f;
}
// fast tanh via hardware exp + rcp: tanh(y) = 1 - 2/(e^{2y}+1)
__device__ inline float fast_tanh(float y) {
  float e = __expf(2.0f * y);                  // v_exp_f32
  float r = __builtin_amdgcn_rcpf(e + 1.0f);   // v_rcp_f32
  return 1.0f - 2.0f * r;
}
// tanh-form GELU (max |err| vs exact-erf GELU ~1e-3 << bf16 rounding)
__device__ inline float gelu_f(float v) {
  float u = 0.7978845608f * v * (1.0f + 0.044715f * v * v);
  return 0.5f * v * (1.0f + fast_tanh(u));
}

// ---------------- degree / CSR build ----------------

__global__ __launch_bounds__(256) void k_degi(const int* __restrict__ dst,
                                              int* __restrict__ cnt, int E) {
  int i = blockIdx.x * 256 + threadIdx.x;
  if (i < E) atomicAdd(&cnt[dst[i]], 1);
}

__global__ __launch_bounds__(256) void k_rdeg(const int* __restrict__ cnt,
                                              float* __restrict__ rdeg, int n) {
  int i = blockIdx.x * 256 + threadIdx.x;
  if (i < n) rdeg[i] = 1.0f / (float)(cnt[i] > 1 ? cnt[i] : 1);
}

__global__ __launch_bounds__(256) void k_scan1(const int* __restrict__ in,
                                               int* __restrict__ out,
                                               int* __restrict__ bsum, int n) {
  __shared__ int sd[256];
  int t = threadIdx.x;
  int base = blockIdx.x * 1024 + t * 4;
  int v[4]; int ts = 0;
  #pragma unroll
  for (int j = 0; j < 4; ++j) { v[j] = (base + j < n) ? in[base + j] : 0; ts += v[j]; }
  sd[t] = ts; __syncthreads();
  for (int off = 1; off < 256; off <<= 1) {
    int x = (t >= off) ? sd[t - off] : 0;
    __syncthreads();
    sd[t] += x;
    __syncthreads();
  }
  int excl = sd[t] - ts;
  #pragma unroll
  for (int j = 0; j < 4; ++j) { if (base + j < n) out[base + j] = excl; excl += v[j]; }
  if (t == 255) bsum[blockIdx.x] = sd[255];
}

__global__ void k_scan2(int* bsum, int nb) {
  __shared__ int sd[256];
  int t = threadIdx.x;
  int v = (t < nb) ? bsum[t] : 0;
  sd[t] = v; __syncthreads();
  for (int off = 1; off < 256; off <<= 1) {
    int x = (t >= off) ? sd[t - off] : 0;
    __syncthreads();
    sd[t] += x;
    __syncthreads();
  }
  if (t < nb) bsum[t] = sd[t] - v;
}

__global__ __launch_bounds__(256) void k_scan3(const int* __restrict__ part,
                                               const int* __restrict__ bsum,
                                               int* __restrict__ rowptr,
                                               int* __restrict__ cursor,
                                               int n, int total) {
  int i = blockIdx.x * 256 + threadIdx.x;
  if (i == 0) rowptr[n] = total;
  if (i < n) { int v = part[i] + bsum[i >> 10]; rowptr[i] = v; cursor[i] = v; }
}

__global__ __launch_bounds__(256) void k_fill(const int* __restrict__ src,
                                              const int* __restrict__ dst,
                                              int* __restrict__ cursor,
                                              int* __restrict__ colidx, int E) {
  int e = blockIdx.x * 256 + threadIdx.x;
  if (e >= E) return;
  int pos = atomicAdd(&cursor[dst[e]], 1);
  colidx[pos] = src[e];
}

// gather-mean over bf16 features: one wave per node, 8 groups of 8 lanes
__global__ __launch_bounds__(256) void k_gather(const unsigned short* __restrict__ x, int ldx,
                                                const int* __restrict__ rowptr,
                                                const int* __restrict__ colidx,
                                                const float* __restrict__ rdeg,
                                                unsigned short* __restrict__ agg, int n) {
  int wave = threadIdx.x >> 6, lane = threadIdx.x & 63;
  int node = blockIdx.x * 4 + wave;
  if (node >= n) return;
  int grp = lane >> 3, c = (lane & 7) * 8;
  int r0 = rowptr[node], r1 = rowptr[node + 1];
  float s[8] = {0.f, 0.f, 0.f, 0.f, 0.f, 0.f, 0.f, 0.f};
  for (int j = r0 + grp; j < r1; j += 8) {
    bf8_t v = *(const bf8_t*)(x + (size_t)colidx[j] * ldx + c);
    #pragma unroll
    for (int jj = 0; jj < 8; ++jj) s[jj] += bf2f((unsigned short)v[jj]);
  }
  #pragma unroll
  for (int jj = 0; jj < 8; ++jj) {
    s[jj] += __shfl_xor(s[jj], 8, 64);
    s[jj] += __shfl_xor(s[jj], 16, 64);
    s[jj] += __shfl_xor(s[jj], 32, 64);
  }
  if (grp == 0) {
    float r = rdeg[node];
    bf8_t o;
    #pragma unroll
    for (int jj = 0; jj < 8; ++jj) o[jj] = (short)f2bf(s[jj] * r);
    *(bf8_t*)(agg + (size_t)node * 64 + c) = o;
  }
}

// ---------------- misc small kernels ----------------

__global__ __launch_bounds__(256) void k_cvt(const float* __restrict__ in,
                                             unsigned short* __restrict__ out, int n) {
  int i = blockIdx.x * 256 + threadIdx.x;
  if (i < n) out[i] = f2bf(in[i]);
}

__global__ __launch_bounds__(256) void k_wt2(const float* __restrict__ W,
                                             unsigned short* __restrict__ Wt,
                                             int K, int N, int total) {
  int i = blockIdx.x * 256 + threadIdx.x;
  if (i >= total) return;
  int n = i / K, k = i - n * K;
  float v = (n < N) ? W[(size_t)k * N + n] : 0.f;
  Wt[i] = f2bf(v);
}

__global__ __launch_bounds__(256) void k_wtsage(const float* __restrict__ Wl,
                                                const float* __restrict__ Wr,
                                                unsigned short* __restrict__ Wt) {
  int i = blockIdx.x * 256 + threadIdx.x;
  if (i >= 3 * 64 * 128) return;
  int l = i >> 13, r = i & 8191, n = r >> 7, k = r & 127;
  float v = (k < 64) ? Wl[l * 4096 + k * 64 + n] : Wr[l * 4096 + (k - 64) * 64 + n];
  Wt[i] = f2bf(v);
}

__global__ __launch_bounds__(256) void k_stats(const float* __restrict__ h,
                                               float* __restrict__ stats, int n) {
  int lane = threadIdx.x & 63, grp = threadIdx.x >> 6;
  float s = 0.f, s2 = 0.f;
  for (int r = blockIdx.x * 4 + grp; r < n; r += gridDim.x * 4) {
    float v = h[(size_t)r * 64 + lane];
    s += v; s2 += v * v;
  }
  __shared__ float l1[4][64], l2[4][64];
  l1[grp][lane] = s; l2[grp][lane] = s2;
  __syncthreads();
  if (grp == 0) {
    s  = l1[0][lane] + l1[1][lane] + l1[2][lane] + l1[3][lane];
    s2 = l2[0][lane] + l2[1][lane] + l2[2][lane] + l2[3][lane];
    atomicAdd(&stats[lane], s);
    atomicAdd(&stats[64 + lane], s2);
  }
}

__global__ void k_statfin(float* stats, const float* __restrict__ ms_, int n) {
  int d = threadIdx.x;
  if (d < 64) {
    float invn = 1.0f / (float)n;
    float m  = stats[d] * invn;
    float e2 = stats[64 + d] * invn;
    float ms = ms_[d];
    float var = e2 - (2.0f * ms - ms * ms) * m * m;
    stats[128 + d] = ms * m;
    stats[192 + d] = rsqrtf(var + 1e-5f);
  }
}

__global__ __launch_bounds__(256) void k_norm(const float* __restrict__ h,
                                              const float* __restrict__ stats,
                                              const float* __restrict__ w,
                                              const float* __restrict__ b,
                                              unsigned short* __restrict__ zcol,
                                              const unsigned short* __restrict__ prev, int n) {
  int i = blockIdx.x * 256 + threadIdx.x;
  if (i >= n * 64) return;
  int r = i >> 6, d = i & 63;
  float v = (h[i] - stats[128 + d]) * stats[192 + d] * w[d] + b[d];
  if (prev) v += bf2f(prev[(size_t)r * 192 + d]);
  zcol[(size_t)r * 192 + d] = f2bf(v);
}

// ---------------- generic bf16 MFMA GEMM (barrier-free, for SAGE) ----------------
template <int NT>
__global__ __launch_bounds__(256) void mgemm(
    const void* __restrict__ A1, int lda1,
    const void* __restrict__ A2, int lda2, int K1, int a_bf16,
    const unsigned short* __restrict__ Wt,
    const float* __restrict__ bias,
    void* __restrict__ Cout, int ldc, int c_bf16, int act,
    int M, int K, int N) {
  int lane = threadIdx.x & 63, wave = threadIdx.x >> 6;
  int quad = lane >> 4, col = lane & 15;
  int row0 = blockIdx.x * 128 + wave * 32;
  int n_base = blockIdx.y * NT * 16;

  f4_t acc[2][NT];
  #pragma unroll
  for (int mt = 0; mt < 2; ++mt)
    #pragma unroll
    for (int nt = 0; nt < NT; ++nt) acc[mt][nt] = (f4_t)0.f;

  int gm[2];
  gm[0] = row0 + col;      if (gm[0] >= M) gm[0] = M - 1;
  gm[1] = row0 + 16 + col; if (gm[1] >= M) gm[1] = M - 1;

  for (int kc0 = 0; kc0 < K; kc0 += 32) {
    int kc = kc0 + quad * 8;
    bf8_t a[2];
    #pragma unroll
    for (int mt = 0; mt < 2; ++mt) {
      const void* src; size_t off;
      if (kc < K1) { src = A1; off = (size_t)gm[mt] * lda1 + kc; }
      else         { src = A2; off = (size_t)gm[mt] * lda2 + kc - K1; }
      if (a_bf16) {
        a[mt] = *(const bf8_t*)((const unsigned short*)src + off);
      } else {
        const float* p = (const float*)src + off;
        float4 f0 = *(const float4*)p;
        float4 f1 = *(const float4*)(p + 4);
        float ff[8] = {f0.x, f0.y, f0.z, f0.w, f1.x, f1.y, f1.z, f1.w};
        #pragma unroll
        for (int j = 0; j < 8; ++j) a[mt][j] = (short)f2bf(ff[j]);
      }
    }
    #pragma unroll
    for (int nt = 0; nt < NT; ++nt) {
      bf8_t b = *(const bf8_t*)(Wt + (size_t)(n_base + nt * 16 + col) * K + kc);
      acc[0][nt] = __builtin_amdgcn_mfma_f32_16x16x32_bf16(a[0], b, acc[0][nt], 0, 0, 0);
      acc[1][nt] = __builtin_amdgcn_mfma_f32_16x16x32_bf16(a[1], b, acc[1][nt], 0, 0, 0);
    }
  }

  #pragma unroll
  for (int nt = 0; nt < NT; ++nt) {
    int n = n_base + nt * 16 + col;
    float bs = (bias && n < N) ? bias[n] : 0.f;
    #pragma unroll
    for (int mt = 0; mt < 2; ++mt)
      #pragma unroll
      for (int r = 0; r < 4; ++r) {
        int row = row0 + mt * 16 + quad * 4 + r;
        if (row >= M || n >= N) continue;
        float v = acc[mt][nt][r] + bs;
        if (act) v = gelu_f(v);
        if (c_bf16) ((unsigned short*)Cout)[(size_t)row * ldc + n] = f2bf(v);
        else        ((float*)Cout)[(size_t)row * ldc + n] = v;
      }
  }
}

// ---------------- block-cooperative fused node pipeline ----------------
// Block = 256 thr = 4 waves = 64 rows; LDS ping-pong A_/B_; wave w owns output
// cols [64w,64w+64). Templated K => fully unrolled k-loop so the compiler
// software-pipelines the 4 weight loads of step s+1 under the MFMAs of step s.
template <int K>
__device__ inline void node_gemm(const unsigned short (*src)[264],
                                 unsigned short (*dst)[264],
                                 const unsigned short* __restrict__ W,
                                 const float* __restrict__ bias,
                                 int wave, int quad, int col,
                                 const float* __restrict__ a2w,
                                 const float* __restrict__ a2b, float ala2) {
  constexpr int KS = K >> 5;
  f4_t acc[4][4];
  #pragma unroll
  for (int mt = 0; mt < 4; ++mt)
    #pragma unroll
    for (int nt = 0; nt < 4; ++nt) acc[mt][nt] = (f4_t)0.f;
  #pragma unroll
  for (int s = 0; s < KS; ++s) {
    int k0 = s * 32 + quad * 8;
    bf8_t b[4];
    #pragma unroll
    for (int nt = 0; nt < 4; ++nt)
      b[nt] = *(const bf8_t*)(W + (size_t)(wave * 64 + nt * 16 + col) * K + k0);
    bf8_t am[4];
    #pragma unroll
    for (int mt = 0; mt < 4; ++mt)
      am[mt] = *(const bf8_t*)&src[mt * 16 + col][k0];
    #pragma unroll
    for (int nt = 0; nt < 4; ++nt)
      #pragma unroll
      for (int mt = 0; mt < 4; ++mt)
        acc[mt][nt] = __builtin_amdgcn_mfma_f32_16x16x32_bf16(am[mt], b[nt], acc[mt][nt], 0, 0, 0);
  }
  #pragma unroll
  for (int nt = 0; nt < 4; ++nt) {
    int n = wave * 64 + nt * 16 + col;
    float bs = bias[n];
    #pragma unroll
    for (int mt = 0; mt < 4; ++mt)
      #pragma unroll
      for (int r4 = 0; r4 < 4; ++r4) {
        float v = gelu_f(acc[mt][nt][r4] + bs);
        if (a2w) v = a2w[n] * fast_tanh(ala2 * v) + a2b[n];
        dst[mt * 16 + quad * 4 + r4][n] = f2bf(v);
      }
  }
  __syncthreads();
}

__global__ __launch_bounds__(256) void k_node(
    const unsigned short* __restrict__ z_bf,
    const float* __restrict__ x_res,
    const float* __restrict__ d1w, const float* __restrict__ d1b, const float* __restrict__ d1a,
    const unsigned short* __restrict__ wt1, const float* __restrict__ b1,
    const unsigned short* __restrict__ wt2, const float* __restrict__ b2,
    const unsigned short* __restrict__ wt3, const float* __restrict__ b3,
    const float* __restrict__ d2w, const float* __restrict__ d2b, const float* __restrict__ d2a,
    const float* __restrict__ a1w, const float* __restrict__ a1b, const float* __restrict__ a1a,
    const unsigned short* __restrict__ wa1, const float* __restrict__ ba1,
    const unsigned short* __restrict__ wa2, const float* __restrict__ ba2,
    const unsigned short* __restrict__ wa3, const float* __restrict__ ba3,
    const float* __restrict__ a2w, const float* __restrict__ a2b, const float* __restrict__ a2a,
    const unsigned short* __restrict__ wa4, const float* __restrict__ ba4,
    unsigned short* __restrict__ zn_bf,
    float* __restrict__ out, int M) {
  __shared__ unsigned short A_[64][264];
  __shared__ unsigned short B_[64][264];
  int t = threadIdx.x;
  int lane = t & 63, wave = t >> 6;
  int quad = lane >> 4, col = lane & 15;
  int row0 = blockIdx.x * 64;

  // ---- stage A_ = dyt1(z rows) ----
  {
    int row = t >> 2, part = t & 3;
    int gr = row0 + row; if (gr >= M) gr = M - 1;
    const unsigned short* zp = z_bf + (size_t)gr * 192 + part * 48;
    float al = d1a[0];
    #pragma unroll
    for (int j = 0; j < 6; ++j) {
      bf8_t v = *(const bf8_t*)(zp + j * 8);
      int k0 = part * 48 + j * 8;
      #pragma unroll
      for (int jj = 0; jj < 8; ++jj) {
        float f = bf2f((unsigned short)v[jj]);
        v[jj] = (short)f2bf(d1w[k0 + jj] * fast_tanh(al * f) + d1b[k0 + jj]);
      }
      *(bf8_t*)&A_[row][k0] = v;
    }
  }
  __syncthreads();

  // ---- lin1 (K=192): A_ -> B_ ----
  node_gemm<192>(A_, B_, wt1, b1, wave, quad, col, nullptr, nullptr, 0.f);
  // ---- lin2 (K=256): B_ -> A_ ----
  node_gemm<256>(B_, A_, wt2, b2, wave, quad, col, nullptr, nullptr, 0.f);

  // ---- lin3 (K=256, N=64; wave w owns n-tile w) + dyt2 + resid + rownorm + adyt1 ----
  {
    f4_t a3[4];
    #pragma unroll
    for (int mt = 0; mt < 4; ++mt) a3[mt] = (f4_t)0.f;
    #pragma unroll
    for (int s = 0; s < 8; ++s) {
      int k0 = s * 32 + quad * 8;
      bf8_t b = *(const bf8_t*)(wt3 + (size_t)(wave * 16 + col) * 256 + k0);
      #pragma unroll
      for (int mt = 0; mt < 4; ++mt) {
        bf8_t am = *(const bf8_t*)&A_[mt * 16 + col][k0];
        a3[mt] = __builtin_amdgcn_mfma_f32_16x16x32_bf16(am, b, a3[mt], 0, 0, 0);
      }
    }
    float* fb = (float*)B_;              // [64][66]
    float al2 = d2a[0];
    int n = wave * 16 + col;
    float bsn = b3[n];
    __syncthreads();
    #pragma unroll
    for (int mt = 0; mt < 4; ++mt)
      #pragma unroll
      for (int r4 = 0; r4 < 4; ++r4) {
        int row = mt * 16 + quad * 4 + r4;
        int gr = row0 + row; if (gr >= M) gr = M - 1;
        float g = gelu_f(a3[mt][r4] + bsn);
        float x = x_res[(size_t)gr * 64 + n];
        fb[row * 66 + n] = d2w[n] * fast_tanh(al2 * g) + d2b[n] + x;
      }
    __syncthreads();
    int row = t >> 2, q = t & 3;
    float s2 = 0.f;
    #pragma unroll
    for (int c16 = 0; c16 < 16; ++c16) {
      float v = fb[row * 66 + q * 16 + c16];
      s2 += v * v;
    }
    float* fp = fb + 64 * 66;
    fp[row * 4 + q] = s2;
    __syncthreads();
    float* fi = fp + 256;
    if (t < 64)
      fi[t] = 1.0f / (sqrtf(fp[t * 4] + fp[t * 4 + 1] + fp[t * 4 + 2] + fp[t * 4 + 3]) + 1e-10f);
    __syncthreads();
    float ala = a1a[0];
    float inv = fi[row];
    int gr = row0 + row;
    int grc = (gr >= M) ? (M - 1) : gr;
    #pragma unroll
    for (int c16 = 0; c16 < 16; ++c16) {
      int c = q * 16 + c16;
      float zv = fb[row * 66 + c] * inv;
      if (gr < M) zn_bf[(size_t)gr * 64 + c] = f2bf(zv);
      A_[row][64 + c] = f2bf(a1w[64 + c] * fast_tanh(ala * zv) + a1b[64 + c]);
      float x = x_res[(size_t)grc * 64 + c];
      A_[row][c] = f2bf(a1w[c] * fast_tanh(ala * x) + a1b[c]);
    }
    __syncthreads();
  }

  // ---- aa1 (K=128): A_ -> B_ ----
  node_gemm<128>(A_, B_, wa1, ba1, wave, quad, col, nullptr, nullptr, 0.f);
  // ---- aa2 (K=256): B_ -> A_ ----
  node_gemm<256>(B_, A_, wa2, ba2, wave, quad, col, nullptr, nullptr, 0.f);
  // ---- aa3 (K=256) + adyt2 epilogue: A_ -> B_ ----
  node_gemm<256>(A_, B_, wa3, ba3, wave, quad, col, a2w, a2b, a2a[0]);

  // ---- aa4 (K=256, N=20 padded 32; wave w owns m-tile w) + log_softmax ----
  {
    f4_t a4[2];
    a4[0] = (f4_t)0.f; a4[1] = (f4_t)0.f;
    #pragma unroll
    for (int s = 0; s < 8; ++s) {
      int k0 = s * 32 + quad * 8;
      bf8_t am = *(const bf8_t*)&B_[wave * 16 + col][k0];
      #pragma unroll
      for (int nt = 0; nt < 2; ++nt) {
        bf8_t b = *(const bf8_t*)(wa4 + (size_t)(nt * 16 + col) * 256 + k0);
        a4[nt] = __builtin_amdgcn_mfma_f32_16x16x32_bf16(am, b, a4[nt], 0, 0, 0);
      }
    }
    float val[2][4];
    #pragma unroll
    for (int nt = 0; nt < 2; ++nt) {
      int n = nt * 16 + col;
      float bsv = (n < 20) ? ba4[n] : 0.f;
      #pragma unroll
      for (int r4 = 0; r4 < 4; ++r4) val[nt][r4] = a4[nt][r4] + bsv;
    }
    bool v1 = (col < 4);
    #pragma unroll
    for (int r4 = 0; r4 < 4; ++r4) {
      float m = val[0][r4];
      if (v1) m = fmaxf(m, val[1][r4]);
      m = fmaxf(m, __shfl_xor(m, 1, 64));
      m = fmaxf(m, __shfl_xor(m, 2, 64));
      m = fmaxf(m, __shfl_xor(m, 4, 64));
      m = fmaxf(m, __shfl_xor(m, 8, 64));
      float se = __expf(val[0][r4] - m) + (v1 ? __expf(val[1][r4] - m) : 0.f);
      se += __shfl_xor(se, 1, 64);
      se += __shfl_xor(se, 2, 64);
      se += __shfl_xor(se, 4, 64);
      se += __shfl_xor(se, 8, 64);
      float ls = __logf(se) + m;
      int row = row0 + wave * 16 + quad * 4 + r4;
      if (row < M) {
        out[(size_t)row * 20 + col] = val[0][r4] - ls;
        if (v1) out[(size_t)row * 20 + 16 + col] = val[1][r4] - ls;
      }
    }
  }
}

// ---------------- fused edge head (prefetching, barrier-free) ----------------
__global__ __launch_bounds__(256) void k_edge(
    const unsigned short* __restrict__ zn_bf,
    const int* __restrict__ ci, const int* __restrict__ cj,
    const unsigned short* __restrict__ w1t, const float* __restrict__ b1,
    const unsigned short* __restrict__ w2t, const float* __restrict__ b2,
    const float* __restrict__ w3, const float* __restrict__ b3,
    float* __restrict__ out, int M) {
  __shared__ unsigned short h1s[4][16][136];
  int lane = threadIdx.x & 63, wave = threadIdx.x >> 6;
  int quad = lane >> 4, col = lane & 15;
  unsigned short (*h1)[136] = h1s[wave];
  int ntiles = (M + 63) >> 6;
  float b3v = b3[0];

  int tile = blockIdx.x;
  bf8_t afrag[4];
  if (tile < ntiles) {
    int r = tile * 64 + wave * 16 + col; if (r >= M) r = M - 1;
    const unsigned short* p0 = zn_bf + (size_t)ci[r] * 64;
    const unsigned short* p1 = zn_bf + (size_t)cj[r] * 64;
    afrag[0] = *(const bf8_t*)(p0 + quad * 8);
    afrag[1] = *(const bf8_t*)(p0 + 32 + quad * 8);
    afrag[2] = *(const bf8_t*)(p1 + quad * 8);
    afrag[3] = *(const bf8_t*)(p1 + 32 + quad * 8);
  }

  for (; tile < ntiles; tile += gridDim.x) {
    f4_t acc[8];
    #pragma unroll
    for (int nt = 0; nt < 8; ++nt) acc[nt] = (f4_t)0.f;
    #pragma unroll
    for (int s = 0; s < 4; ++s) {
      int kf = s * 32 + quad * 8;
      #pragma unroll
      for (int nt = 0; nt < 8; ++nt) {
        bf8_t b = *(const bf8_t*)(w1t + (size_t)(nt * 16 + col) * 128 + kf);
        acc[nt] = __builtin_amdgcn_mfma_f32_16x16x32_bf16(afrag[s], b, acc[nt], 0, 0, 0);
      }
    }

    int nxt = tile + gridDim.x;
    bf8_t nfrag[4];
    bool has_next = (nxt < ntiles);
    if (has_next) {
      int r = nxt * 64 + wave * 16 + col; if (r >= M) r = M - 1;
      const unsigned short* p0 = zn_bf + (size_t)ci[r] * 64;
      const unsigned short* p1 = zn_bf + (size_t)cj[r] * 64;
      nfrag[0] = *(const bf8_t*)(p0 + quad * 8);
      nfrag[1] = *(const bf8_t*)(p0 + 32 + quad * 8);
      nfrag[2] = *(const bf8_t*)(p1 + quad * 8);
      nfrag[3] = *(const bf8_t*)(p1 + 32 + quad * 8);
    }

    #pragma unroll
    for (int nt = 0; nt < 8; ++nt) {
      float bs = b1[nt * 16 + col];
      #pragma unroll
      for (int r4 = 0; r4 < 4; ++r4)
        h1[quad * 4 + r4][nt * 16 + col] = f2bf(gelu_f(acc[nt][r4] + bs));
    }

    f4_t a2[8];
    #pragma unroll
    for (int nt = 0; nt < 8; ++nt) a2[nt] = (f4_t)0.f;
    #pragma unroll
    for (int s = 0; s < 4; ++s) {
      int kc = s * 32 + quad * 8;
      bf8_t a0 = *(const bf8_t*)&h1[col][kc];
      #pragma unroll
      for (int nt = 0; nt < 8; ++nt) {
        bf8_t b = *(const bf8_t*)(w2t + (size_t)(nt * 16 + col) * 128 + kc);
        a2[nt] = __builtin_amdgcn_mfma_f32_16x16x32_bf16(a0, b, a2[nt], 0, 0, 0);
      }
    }
    float p[4] = {0.f, 0.f, 0.f, 0.f};
    #pragma unroll
    for (int nt = 0; nt < 8; ++nt) {
      float bs = b2[nt * 16 + col];
      float wv = w3[nt * 16 + col];
      #pragma unroll
      for (int r4 = 0; r4 < 4; ++r4)
        p[r4] += gelu_f(a2[nt][r4] + bs) * wv;
    }
    #pragma unroll
    for (int r4 = 0; r4 < 4; ++r4) {
      float s = p[r4];
      s += __shfl_xor(s, 1, 64);
      s += __shfl_xor(s, 2, 64);
      s += __shfl_xor(s, 4, 64);
      s += __shfl_xor(s, 8, 64);
      if (col == 0) {
        int row = tile * 64 + wave * 16 + quad * 4 + r4;
        if (row < M) out[row] = __builtin_amdgcn_rcpf(1.0f + __expf(-(s + b3v)));
      }
    }

    if (has_next) {
      afrag[0] = nfrag[0]; afrag[1] = nfrag[1];
      afrag[2] = nfrag[2]; afrag[3] = nfrag[3];
    }
  }
}

// ---------------- launcher ----------------
extern "C" void kernel_launch(void* const* d_in, const int* in_sizes, int n_in,
                              void* d_out, int out_size, void* d_ws, size_t ws_size,
                              hipStream_t stream) {
  const float* x_res  = (const float*)d_in[0];
  const float* Wl     = (const float*)d_in[1];
  const float* bl     = (const float*)d_in[2];
  const float* Wr     = (const float*)d_in[3];
  const float* gn_w   = (const float*)d_in[4];
  const float* gn_b   = (const float*)d_in[5];
  const float* gn_ms  = (const float*)d_in[6];
  const float* dyt1_w = (const float*)d_in[7];
  const float* dyt1_b = (const float*)d_in[8];
  const float* dyt1_a = (const float*)d_in[9];
  const float* lin1_w = (const float*)d_in[10];
  const float* lin1_b = (const float*)d_in[11];
  const float* lin2_w = (const float*)d_in[12];
  const float* lin2_b = (const float*)d_in[13];
  const float* lin3_w = (const float*)d_in[14];
  const float* lin3_b = (const float*)d_in[15];
  const float* dyt2_w = (const float*)d_in[16];
  const float* dyt2_b = (const float*)d_in[17];
  const float* dyt2_a = (const float*)d_in[18];
  const float* adyt1_w = (const float*)d_in[19];
  const float* adyt1_b = (const float*)d_in[20];
  const float* adyt1_a = (const float*)d_in[21];
  const float* aa1_w  = (const float*)d_in[22];
  const float* aa1_b  = (const float*)d_in[23];
  const float* aa2_w  = (const float*)d_in[24];
  const float* aa2_b  = (const float*)d_in[25];
  const float* aa3_w  = (const float*)d_in[26];
  const float* aa3_b  = (const float*)d_in[27];
  const float* adyt2_w = (const float*)d_in[28];
  const float* adyt2_b = (const float*)d_in[29];
  const float* adyt2_a = (const float*)d_in[30];
  const float* aa4_w  = (const float*)d_in[31];
  const float* aa4_b  = (const float*)d_in[32];
  const float* c1_w   = (const float*)d_in[33];
  const float* c1_b   = (const float*)d_in[34];
  const float* c2_w   = (const float*)d_in[35];
  const float* c2_b   = (const float*)d_in[36];
  const float* c3_w   = (const float*)d_in[37];
  const float* c3_b   = (const float*)d_in[38];
  const int*   edge   = (const int*)d_in[39];
  const int*   contact = (const int*)d_in[40];

  const size_t N = (size_t)Nn;
  const size_t ws_floats = ws_size / 4;

  float* ws    = (float*)d_ws;
  float* rdeg  = ws;
  float* hbuf  = rdeg + N;
  unsigned short* z_bf  = (unsigned short*)(hbuf + 64 * N);
  unsigned short* zn_bf = z_bf + 192 * N;
  float* stats = (float*)(zn_bf + 64 * N);
  unsigned short* wt_sage = (unsigned short*)(stats + 256);
  unsigned short* wt_lin1 = wt_sage + 3 * 64 * 128;
  unsigned short* wt_lin2 = wt_lin1 + 256 * 192;
  unsigned short* wt_lin3 = wt_lin2 + 256 * 256;
  unsigned short* wt_aa1  = wt_lin3 + 64 * 256;
  unsigned short* wt_aa2  = wt_aa1 + 256 * 128;
  unsigned short* wt_aa3  = wt_aa2 + 256 * 256;
  unsigned short* wt_aa4  = wt_aa3 + 256 * 256;
  unsigned short* wt_c1   = wt_aa4 + 32 * 256;
  unsigned short* wt_c2   = wt_c1 + 128 * 128;
  unsigned short* wt_end  = wt_c2 + 128 * 128;
  float* pool  = (float*)((((uintptr_t)wt_end + 15) & ~(uintptr_t)15));
  const size_t persist = (size_t)(pool - ws);

  const size_t gnn_need = 32 * N + N + (N + 1) + N + (size_t)Ee + 256;
  if (ws_floats < persist + gnn_need) return;

  unsigned short* agg_bf = (unsigned short*)pool;
  int* cnt     = (int*)(pool + 32 * N);
  int* rowptr  = cnt + N;
  int* cursor  = rowptr + N + 1;
  int* colidx  = cursor + N;
  int* bsum    = colidx + Ee;

  const int* esrc = edge;
  const int* edst = edge + Ee;

  // ---- CSR build ----
  hipMemsetAsync(cnt, 0, N * sizeof(int), stream);
  k_degi<<<(Ee + 255) / 256, 256, 0, stream>>>(edst, cnt, Ee);
  k_rdeg<<<(Nn + 255) / 256, 256, 0, stream>>>(cnt, rdeg, Nn);
  const int nb = (Nn + 1023) / 1024;
  k_scan1<<<nb, 256, 0, stream>>>(cnt, cursor, bsum, Nn);
  k_scan2<<<1, 256, 0, stream>>>(bsum, nb);
  k_scan3<<<(Nn + 255) / 256, 256, 0, stream>>>(cursor, bsum, rowptr, cursor, Nn, Ee);
  k_fill<<<(Ee + 255) / 256, 256, 0, stream>>>(esrc, edst, cursor, colidx, Ee);

  // ---- weight prep ----
  k_wtsage<<<(3 * 64 * 128 + 255) / 256, 256, 0, stream>>>(Wl, Wr, wt_sage);
  k_wt2<<<(256 * 192 + 255) / 256, 256, 0, stream>>>(lin1_w, wt_lin1, 192, 256, 256 * 192);
  k_wt2<<<(256 * 256 + 255) / 256, 256, 0, stream>>>(lin2_w, wt_lin2, 256, 256, 256 * 256);
  k_wt2<<<(64 * 256 + 255) / 256, 256, 0, stream>>>(lin3_w, wt_lin3, 256, 64, 64 * 256);
  k_wt2<<<(256 * 128 + 255) / 256, 256, 0, stream>>>(aa1_w, wt_aa1, 128, 256, 256 * 128);
  k_wt2<<<(256 * 256 + 255) / 256, 256, 0, stream>>>(aa2_w, wt_aa2, 256, 256, 256 * 256);
  k_wt2<<<(256 * 256 + 255) / 256, 256, 0, stream>>>(aa3_w, wt_aa3, 256, 256, 256 * 256);
  k_wt2<<<(32 * 256 + 255) / 256, 256, 0, stream>>>(aa4_w, wt_aa4, 256, 20, 32 * 256);
  k_wt2<<<(128 * 128 + 255) / 256, 256, 0, stream>>>(c1_w, wt_c1, 128, 128, 128 * 128);
  k_wt2<<<(128 * 128 + 255) / 256, 256, 0, stream>>>(c2_w, wt_c2, 128, 128, 128 * 128);

  // xb = bf16(x_res) in zn_bf slot
  k_cvt<<<(int)((N * 64 + 255) / 256), 256, 0, stream>>>(x_res, zn_bf, (int)(N * 64));

  // ---- GNN phase ----
  for (int l = 0; l < 3; ++l) {
    const unsigned short* xi = (l == 0) ? zn_bf : (z_bf + (size_t)(l - 1) * 64);
    int ldx = (l == 0) ? 64 : 192;
    hipMemsetAsync(stats, 0, 128 * sizeof(float), stream);
    k_gather<<<(Nn + 3) / 4, 256, 0, stream>>>(xi, ldx, rowptr, colidx, rdeg, agg_bf, Nn);
    mgemm<4><<<dim3((Nn + 127) / 128, 1), 256, 0, stream>>>(
        agg_bf, 64, xi, ldx, 64, 1,
        wt_sage + (size_t)l * 8192, bl + l * 64, hbuf, 64, 0, 1, Nn, 128, 64);
    k_stats<<<1024, 256, 0, stream>>>(hbuf, stats, Nn);
    k_statfin<<<1, 64, 0, stream>>>(stats, gn_ms + l * 64, Nn);
    k_norm<<<(Nn * 64) / 256, 256, 0, stream>>>(hbuf, stats, gn_w + l * 64, gn_b + l * 64,
                                                z_bf + (size_t)l * 64,
                                                (l > 0) ? (z_bf + (size_t)(l - 1) * 64) : nullptr, Nn);
  }

  // ---- block-cooperative fused node pipeline ----
  k_node<<<(Nn + 63) / 64, 256, 0, stream>>>(
      z_bf, x_res,
      dyt1_w, dyt1_b, dyt1_a, wt_lin1, lin1_b, wt_lin2, lin2_b, wt_lin3, lin3_b,
      dyt2_w, dyt2_b, dyt2_a,
      adyt1_w, adyt1_b, adyt1_a, wt_aa1, aa1_b, wt_aa2, aa2_b, wt_aa3, aa3_b,
      adyt2_w, adyt2_b, adyt2_a, wt_aa4, aa4_b,
      zn_bf, (float*)d_out, Nn);

  // ---- fused edge head ----
  float* eout = (float*)d_out + (size_t)Nn * 20;
  k_edge<<<2048, 256, 0, stream>>>(zn_bf, contact, contact + EPp,
      wt_c1, c1_b, wt_c2, c2_b, c3_w, c3_b, eout, EPp);
}

// Round 8
// 1939.815 us; speedup vs baseline: 1.4684x; 1.0230x over previous
//
#include <hip/hip_runtime.h>
#include <cstdint>
#include <cstddef>

// ---------------- problem constants ----------------
constexpr int Nn  = 200000;
constexpr int Ee  = 1600000;
constexpr int EPp = 1000000;

typedef __attribute__((ext_vector_type(8))) short bf8_t;
typedef __attribute__((ext_vector_type(4))) float f4_t;

__device__ inline unsigned short f2bf(float f) {
  union { float f; unsigned u; } v; v.f = f;
  unsigned r = v.u + 0x7FFFu + ((v.u >> 16) & 1u);
  return (unsigned short)(r >> 16);
}
__device__ inline float bf2f(unsigned short u) {
  union { unsigned u; float f; } v; v.u = ((unsigned)u) << 16;
  return v.f;
}
// fast tanh via hardware exp + rcp: tanh(y) = 1 - 2/(e^{2y}+1)
__device__ inline float fast_tanh(float y) {
  float e = __expf(2.0f * y);
  float r = __builtin_amdgcn_rcpf(e + 1.0f);
  return 1.0f - 2.0f * r;
}
// tanh-form GELU (max |err| vs exact-erf GELU ~1e-3 << bf16 rounding)
__device__ inline float gelu_f(float v) {
  float u = 0.7978845608f * v * (1.0f + 0.044715f * v * v);
  return 0.5f * v * (1.0f + fast_tanh(u));
}

// ---------------- degree / CSR build ----------------

__global__ __launch_bounds__(256) void k_degi(const int* __restrict__ dst,
                                              int* __restrict__ cnt, int E) {
  int i = blockIdx.x * 256 + threadIdx.x;
  if (i < E) atomicAdd(&cnt[dst[i]], 1);
}

__global__ __launch_bounds__(256) void k_rdeg(const int* __restrict__ cnt,
                                              float* __restrict__ rdeg, int n) {
  int i = blockIdx.x * 256 + threadIdx.x;
  if (i < n) rdeg[i] = 1.0f / (float)(cnt[i] > 1 ? cnt[i] : 1);
}

__global__ __launch_bounds__(256) void k_scan1(const int* __restrict__ in,
                                               int* __restrict__ out,
                                               int* __restrict__ bsum, int n) {
  __shared__ int sd[256];
  int t = threadIdx.x;
  int base = blockIdx.x * 1024 + t * 4;
  int v[4]; int ts = 0;
  #pragma unroll
  for (int j = 0; j < 4; ++j) { v[j] = (base + j < n) ? in[base + j] : 0; ts += v[j]; }
  sd[t] = ts; __syncthreads();
  for (int off = 1; off < 256; off <<= 1) {
    int x = (t >= off) ? sd[t - off] : 0;
    __syncthreads();
    sd[t] += x;
    __syncthreads();
  }
  int excl = sd[t] - ts;
  #pragma unroll
  for (int j = 0; j < 4; ++j) { if (base + j < n) out[base + j] = excl; excl += v[j]; }
  if (t == 255) bsum[blockIdx.x] = sd[255];
}

__global__ void k_scan2(int* bsum, int nb) {
  __shared__ int sd[256];
  int t = threadIdx.x;
  int v = (t < nb) ? bsum[t] : 0;
  sd[t] = v; __syncthreads();
  for (int off = 1; off < 256; off <<= 1) {
    int x = (t >= off) ? sd[t - off] : 0;
    __syncthreads();
    sd[t] += x;
    __syncthreads();
  }
  if (t < nb) bsum[t] = sd[t] - v;
}

__global__ __launch_bounds__(256) void k_scan3(const int* __restrict__ part,
                                               const int* __restrict__ bsum,
                                               int* __restrict__ rowptr,
                                               int* __restrict__ cursor,
                                               int n, int total) {
  int i = blockIdx.x * 256 + threadIdx.x;
  if (i == 0) rowptr[n] = total;
  if (i < n) { int v = part[i] + bsum[i >> 10]; rowptr[i] = v; cursor[i] = v; }
}

__global__ __launch_bounds__(256) void k_fill(const int* __restrict__ src,
                                              const int* __restrict__ dst,
                                              int* __restrict__ cursor,
                                              int* __restrict__ colidx, int E) {
  int e = blockIdx.x * 256 + threadIdx.x;
  if (e >= E) return;
  int pos = atomicAdd(&cursor[dst[e]], 1);
  colidx[pos] = src[e];
}

// gather-mean over bf16 features: one wave per node, 8 groups of 8 lanes
__global__ __launch_bounds__(256) void k_gather(const unsigned short* __restrict__ x, int ldx,
                                                const int* __restrict__ rowptr,
                                                const int* __restrict__ colidx,
                                                const float* __restrict__ rdeg,
                                                unsigned short* __restrict__ agg, int n) {
  int wave = threadIdx.x >> 6, lane = threadIdx.x & 63;
  int node = blockIdx.x * 4 + wave;
  if (node >= n) return;
  int grp = lane >> 3, c = (lane & 7) * 8;
  int r0 = rowptr[node], r1 = rowptr[node + 1];
  float s[8] = {0.f, 0.f, 0.f, 0.f, 0.f, 0.f, 0.f, 0.f};
  for (int j = r0 + grp; j < r1; j += 8) {
    bf8_t v = *(const bf8_t*)(x + (size_t)colidx[j] * ldx + c);
    #pragma unroll
    for (int jj = 0; jj < 8; ++jj) s[jj] += bf2f((unsigned short)v[jj]);
  }
  #pragma unroll
  for (int jj = 0; jj < 8; ++jj) {
    s[jj] += __shfl_xor(s[jj], 8, 64);
    s[jj] += __shfl_xor(s[jj], 16, 64);
    s[jj] += __shfl_xor(s[jj], 32, 64);
  }
  if (grp == 0) {
    float r = rdeg[node];
    bf8_t o;
    #pragma unroll
    for (int jj = 0; jj < 8; ++jj) o[jj] = (short)f2bf(s[jj] * r);
    *(bf8_t*)(agg + (size_t)node * 64 + c) = o;
  }
}

// ---------------- misc small kernels ----------------

__global__ __launch_bounds__(256) void k_cvt(const float* __restrict__ in,
                                             unsigned short* __restrict__ out, int n) {
  int i = blockIdx.x * 256 + threadIdx.x;
  if (i < n) out[i] = f2bf(in[i]);
}

__global__ __launch_bounds__(256) void k_wt2(const float* __restrict__ W,
                                             unsigned short* __restrict__ Wt,
                                             int K, int N, int total) {
  int i = blockIdx.x * 256 + threadIdx.x;
  if (i >= total) return;
  int n = i / K, k = i - n * K;
  float v = (n < N) ? W[(size_t)k * N + n] : 0.f;
  Wt[i] = f2bf(v);
}

__global__ __launch_bounds__(256) void k_wtsage(const float* __restrict__ Wl,
                                                const float* __restrict__ Wr,
                                                unsigned short* __restrict__ Wt) {
  int i = blockIdx.x * 256 + threadIdx.x;
  if (i >= 3 * 64 * 128) return;
  int l = i >> 13, r = i & 8191, n = r >> 7, k = r & 127;
  float v = (k < 64) ? Wl[l * 4096 + k * 64 + n] : Wr[l * 4096 + (k - 64) * 64 + n];
  Wt[i] = f2bf(v);
}

__global__ __launch_bounds__(256) void k_stats(const float* __restrict__ h,
                                               float* __restrict__ stats, int n) {
  int lane = threadIdx.x & 63, grp = threadIdx.x >> 6;
  float s = 0.f, s2 = 0.f;
  for (int r = blockIdx.x * 4 + grp; r < n; r += gridDim.x * 4) {
    float v = h[(size_t)r * 64 + lane];
    s += v; s2 += v * v;
  }
  __shared__ float l1[4][64], l2[4][64];
  l1[grp][lane] = s; l2[grp][lane] = s2;
  __syncthreads();
  if (grp == 0) {
    s  = l1[0][lane] + l1[1][lane] + l1[2][lane] + l1[3][lane];
    s2 = l2[0][lane] + l2[1][lane] + l2[2][lane] + l2[3][lane];
    atomicAdd(&stats[lane], s);
    atomicAdd(&stats[64 + lane], s2);
  }
}

__global__ void k_statfin(float* stats, const float* __restrict__ ms_, int n) {
  int d = threadIdx.x;
  if (d < 64) {
    float invn = 1.0f / (float)n;
    float m  = stats[d] * invn;
    float e2 = stats[64 + d] * invn;
    float ms = ms_[d];
    float var = e2 - (2.0f * ms - ms * ms) * m * m;
    stats[128 + d] = ms * m;
    stats[192 + d] = rsqrtf(var + 1e-5f);
  }
}

__global__ __launch_bounds__(256) void k_norm(const float* __restrict__ h,
                                              const float* __restrict__ stats,
                                              const float* __restrict__ w,
                                              const float* __restrict__ b,
                                              unsigned short* __restrict__ zcol,
                                              const unsigned short* __restrict__ prev, int n) {
  int i = blockIdx.x * 256 + threadIdx.x;
  if (i >= n * 64) return;
  int r = i >> 6, d = i & 63;
  float v = (h[i] - stats[128 + d]) * stats[192 + d] * w[d] + b[d];
  if (prev) v += bf2f(prev[(size_t)r * 192 + d]);
  zcol[(size_t)r * 192 + d] = f2bf(v);
}

// ---------------- generic bf16 MFMA GEMM (barrier-free, for SAGE) ----------------
template <int NT>
__global__ __launch_bounds__(256) void mgemm(
    const void* __restrict__ A1, int lda1,
    const void* __restrict__ A2, int lda2, int K1, int a_bf16,
    const unsigned short* __restrict__ Wt,
    const float* __restrict__ bias,
    void* __restrict__ Cout, int ldc, int c_bf16, int act,
    int M, int K, int N) {
  int lane = threadIdx.x & 63, wave = threadIdx.x >> 6;
  int quad = lane >> 4, col = lane & 15;
  int row0 = blockIdx.x * 128 + wave * 32;
  int n_base = blockIdx.y * NT * 16;

  f4_t acc[2][NT];
  #pragma unroll
  for (int mt = 0; mt < 2; ++mt)
    #pragma unroll
    for (int nt = 0; nt < NT; ++nt) acc[mt][nt] = (f4_t)0.f;

  int gm[2];
  gm[0] = row0 + col;      if (gm[0] >= M) gm[0] = M - 1;
  gm[1] = row0 + 16 + col; if (gm[1] >= M) gm[1] = M - 1;

  for (int kc0 = 0; kc0 < K; kc0 += 32) {
    int kc = kc0 + quad * 8;
    bf8_t a[2];
    #pragma unroll
    for (int mt = 0; mt < 2; ++mt) {
      const void* src; size_t off;
      if (kc < K1) { src = A1; off = (size_t)gm[mt] * lda1 + kc; }
      else         { src = A2; off = (size_t)gm[mt] * lda2 + kc - K1; }
      if (a_bf16) {
        a[mt] = *(const bf8_t*)((const unsigned short*)src + off);
      } else {
        const float* p = (const float*)src + off;
        float4 f0 = *(const float4*)p;
        float4 f1 = *(const float4*)(p + 4);
        float ff[8] = {f0.x, f0.y, f0.z, f0.w, f1.x, f1.y, f1.z, f1.w};
        #pragma unroll
        for (int j = 0; j < 8; ++j) a[mt][j] = (short)f2bf(ff[j]);
      }
    }
    #pragma unroll
    for (int nt = 0; nt < NT; ++nt) {
      bf8_t b = *(const bf8_t*)(Wt + (size_t)(n_base + nt * 16 + col) * K + kc);
      acc[0][nt] = __builtin_amdgcn_mfma_f32_16x16x32_bf16(a[0], b, acc[0][nt], 0, 0, 0);
      acc[1][nt] = __builtin_amdgcn_mfma_f32_16x16x32_bf16(a[1], b, acc[1][nt], 0, 0, 0);
    }
  }

  #pragma unroll
  for (int nt = 0; nt < NT; ++nt) {
    int n = n_base + nt * 16 + col;
    float bs = (bias && n < N) ? bias[n] : 0.f;
    #pragma unroll
    for (int mt = 0; mt < 2; ++mt)
      #pragma unroll
      for (int r = 0; r < 4; ++r) {
        int row = row0 + mt * 16 + quad * 4 + r;
        if (row >= M || n >= N) continue;
        float v = acc[mt][nt][r] + bs;
        if (act) v = gelu_f(v);
        if (c_bf16) ((unsigned short*)Cout)[(size_t)row * ldc + n] = f2bf(v);
        else        ((float*)Cout)[(size_t)row * ldc + n] = v;
      }
  }
}

// ---------------- block-cooperative fused node pipeline (single LDS buffer) ----
// Block = 256 thr = 4 waves = 64 rows. ONE activation buffer H[64][264]
// (35 KB total LDS -> 3 blocks/CU instead of ~1 at 67.5 KB). Per layer: all
// LDS reads happen in the k-loop, all writes in the epilogue; two barriers
// make read/write phases disjoint. Wave w owns output cols [64w, 64w+64).
template <int K>
__device__ inline void node_gemm(unsigned short (*H)[264],
                                 const unsigned short* __restrict__ W,
                                 const float* __restrict__ bias,
                                 int wave, int quad, int col,
                                 const float* __restrict__ a2w,
                                 const float* __restrict__ a2b, float ala2) {
  constexpr int KS = K >> 5;
  f4_t acc[4][4];
  #pragma unroll
  for (int mt = 0; mt < 4; ++mt)
    #pragma unroll
    for (int nt = 0; nt < 4; ++nt) acc[mt][nt] = (f4_t)0.f;
  #pragma unroll
  for (int s = 0; s < KS; ++s) {
    int k0 = s * 32 + quad * 8;
    bf8_t b[4];
    #pragma unroll
    for (int nt = 0; nt < 4; ++nt)
      b[nt] = *(const bf8_t*)(W + (size_t)(wave * 64 + nt * 16 + col) * K + k0);
    bf8_t am[4];
    #pragma unroll
    for (int mt = 0; mt < 4; ++mt)
      am[mt] = *(const bf8_t*)&H[mt * 16 + col][k0];
    #pragma unroll
    for (int nt = 0; nt < 4; ++nt)
      #pragma unroll
      for (int mt = 0; mt < 4; ++mt)
        acc[mt][nt] = __builtin_amdgcn_mfma_f32_16x16x32_bf16(am[mt], b[nt], acc[mt][nt], 0, 0, 0);
  }
  __syncthreads();   // all reads of H complete before epilogue writes
  #pragma unroll
  for (int nt = 0; nt < 4; ++nt) {
    int n = wave * 64 + nt * 16 + col;
    float bs = bias[n];
    #pragma unroll
    for (int mt = 0; mt < 4; ++mt)
      #pragma unroll
      for (int r4 = 0; r4 < 4; ++r4) {
        float v = gelu_f(acc[mt][nt][r4] + bs);
        if (a2w) v = a2w[n] * fast_tanh(ala2 * v) + a2b[n];
        H[mt * 16 + quad * 4 + r4][n] = f2bf(v);
      }
  }
  __syncthreads();
}

__global__ __launch_bounds__(256) void k_node(
    const unsigned short* __restrict__ z_bf,
    const float* __restrict__ x_res,
    const float* __restrict__ d1w, const float* __restrict__ d1b, const float* __restrict__ d1a,
    const unsigned short* __restrict__ wt1, const float* __restrict__ b1,
    const unsigned short* __restrict__ wt2, const float* __restrict__ b2,
    const unsigned short* __restrict__ wt3, const float* __restrict__ b3,
    const float* __restrict__ d2w, const float* __restrict__ d2b, const float* __restrict__ d2a,
    const float* __restrict__ a1w, const float* __restrict__ a1b, const float* __restrict__ a1a,
    const unsigned short* __restrict__ wa1, const float* __restrict__ ba1,
    const unsigned short* __restrict__ wa2, const float* __restrict__ ba2,
    const unsigned short* __restrict__ wa3, const float* __restrict__ ba3,
    const float* __restrict__ a2w, const float* __restrict__ a2b, const float* __restrict__ a2a,
    const unsigned short* __restrict__ wa4, const float* __restrict__ ba4,
    unsigned short* __restrict__ zn_bf,
    float* __restrict__ out, int M) {
  __shared__ unsigned short H[64][264];   // 33.8 KB — the only big buffer
  __shared__ float fscr[64 * 4 + 64];     // rownorm partials + inv norms
  int t = threadIdx.x;
  int lane = t & 63, wave = t >> 6;
  int quad = lane >> 4, col = lane & 15;
  int row0 = blockIdx.x * 64;

  // ---- stage H = dyt1(z rows) ----
  {
    int row = t >> 2, part = t & 3;
    int gr = row0 + row; if (gr >= M) gr = M - 1;
    const unsigned short* zp = z_bf + (size_t)gr * 192 + part * 48;
    float al = d1a[0];
    #pragma unroll
    for (int j = 0; j < 6; ++j) {
      bf8_t v = *(const bf8_t*)(zp + j * 8);
      int k0 = part * 48 + j * 8;
      #pragma unroll
      for (int jj = 0; jj < 8; ++jj) {
        float f = bf2f((unsigned short)v[jj]);
        v[jj] = (short)f2bf(d1w[k0 + jj] * fast_tanh(al * f) + d1b[k0 + jj]);
      }
      *(bf8_t*)&H[row][k0] = v;
    }
  }
  __syncthreads();

  // ---- lin1 (K=192), lin2 (K=256) ----
  node_gemm<192>(H, wt1, b1, wave, quad, col, nullptr, nullptr, 0.f);
  node_gemm<256>(H, wt2, b2, wave, quad, col, nullptr, nullptr, 0.f);

  // ---- lin3 (K=256, N=64; wave w owns n-tile w) + dyt2 + resid + rownorm + adyt1 ----
  {
    f4_t a3[4];
    #pragma unroll
    for (int mt = 0; mt < 4; ++mt) a3[mt] = (f4_t)0.f;
    #pragma unroll
    for (int s = 0; s < 8; ++s) {
      int k0 = s * 32 + quad * 8;
      bf8_t b = *(const bf8_t*)(wt3 + (size_t)(wave * 16 + col) * 256 + k0);
      #pragma unroll
      for (int mt = 0; mt < 4; ++mt) {
        bf8_t am = *(const bf8_t*)&H[mt * 16 + col][k0];
        a3[mt] = __builtin_amdgcn_mfma_f32_16x16x32_bf16(am, b, a3[mt], 0, 0, 0);
      }
    }
    __syncthreads();                     // all lin3 reads of H complete
    // vv (fp32) overlaid into H's storage ([64][66] floats)
    float* fb = (float*)H;
    float al2 = d2a[0];
    int n = wave * 16 + col;
    float bsn = b3[n];
    #pragma unroll
    for (int mt = 0; mt < 4; ++mt)
      #pragma unroll
      for (int r4 = 0; r4 < 4; ++r4) {
        int row = mt * 16 + quad * 4 + r4;
        int gr = row0 + row; if (gr >= M) gr = M - 1;
        float g = gelu_f(a3[mt][r4] + bsn);
        float x = x_res[(size_t)gr * 64 + n];
        fb[row * 66 + n] = d2w[n] * fast_tanh(al2 * g) + d2b[n] + x;
      }
    __syncthreads();
    // each thread owns (row = t>>2, cols q*16..q*16+15): read to REGISTERS
    int row = t >> 2, q = t & 3;
    float vreg[16];
    float s2 = 0.f;
    #pragma unroll
    for (int c16 = 0; c16 < 16; ++c16) {
      vreg[c16] = fb[row * 66 + q * 16 + c16];
      s2 += vreg[c16] * vreg[c16];
    }
    fscr[row * 4 + q] = s2;
    __syncthreads();
    if (t < 64)
      fscr[256 + t] = 1.0f / (sqrtf(fscr[t * 4] + fscr[t * 4 + 1] + fscr[t * 4 + 2] + fscr[t * 4 + 3]) + 1e-10f);
    __syncthreads();                     // all fb reads complete; inv ready
    // write adyt1([x_res, zn]) into H (bf16 view) from registers; write zn_bf
    float ala = a1a[0];
    float inv = fscr[256 + row];
    int gr = row0 + row;
    int grc = (gr >= M) ? (M - 1) : gr;
    #pragma unroll
    for (int c16 = 0; c16 < 16; ++c16) {
      int c = q * 16 + c16;
      float zv = vreg[c16] * inv;
      if (gr < M) zn_bf[(size_t)gr * 64 + c] = f2bf(zv);
      H[row][64 + c] = f2bf(a1w[64 + c] * fast_tanh(ala * zv) + a1b[64 + c]);
      float x = x_res[(size_t)grc * 64 + c];
      H[row][c] = f2bf(a1w[c] * fast_tanh(ala * x) + a1b[c]);
    }
    __syncthreads();
  }

  // ---- aa1 (K=128), aa2 (K=256), aa3 (K=256, adyt2 epilogue) ----
  node_gemm<128>(H, wa1, ba1, wave, quad, col, nullptr, nullptr, 0.f);
  node_gemm<256>(H, wa2, ba2, wave, quad, col, nullptr, nullptr, 0.f);
  node_gemm<256>(H, wa3, ba3, wave, quad, col, a2w, a2b, a2a[0]);

  // ---- aa4 (K=256, N=20 padded 32; wave w owns m-tile w) + log_softmax ----
  {
    f4_t a4[2];
    a4[0] = (f4_t)0.f; a4[1] = (f4_t)0.f;
    #pragma unroll
    for (int s = 0; s < 8; ++s) {
      int k0 = s * 32 + quad * 8;
      bf8_t am = *(const bf8_t*)&H[wave * 16 + col][k0];
      #pragma unroll
      for (int nt = 0; nt < 2; ++nt) {
        bf8_t b = *(const bf8_t*)(wa4 + (size_t)(nt * 16 + col) * 256 + k0);
        a4[nt] = __builtin_amdgcn_mfma_f32_16x16x32_bf16(am, b, a4[nt], 0, 0, 0);
      }
    }
    float val[2][4];
    #pragma unroll
    for (int nt = 0; nt < 2; ++nt) {
      int n = nt * 16 + col;
      float bsv = (n < 20) ? ba4[n] : 0.f;
      #pragma unroll
      for (int r4 = 0; r4 < 4; ++r4) val[nt][r4] = a4[nt][r4] + bsv;
    }
    bool v1 = (col < 4);
    #pragma unroll
    for (int r4 = 0; r4 < 4; ++r4) {
      float m = val[0][r4];
      if (v1) m = fmaxf(m, val[1][r4]);
      m = fmaxf(m, __shfl_xor(m, 1, 64));
      m = fmaxf(m, __shfl_xor(m, 2, 64));
      m = fmaxf(m, __shfl_xor(m, 4, 64));
      m = fmaxf(m, __shfl_xor(m, 8, 64));
      float se = __expf(val[0][r4] - m) + (v1 ? __expf(val[1][r4] - m) : 0.f);
      se += __shfl_xor(se, 1, 64);
      se += __shfl_xor(se, 2, 64);
      se += __shfl_xor(se, 4, 64);
      se += __shfl_xor(se, 8, 64);
      float ls = __logf(se) + m;
      int row = row0 + wave * 16 + quad * 4 + r4;
      if (row < M) {
        out[(size_t)row * 20 + col] = val[0][r4] - ls;
        if (v1) out[(size_t)row * 20 + 16 + col] = val[1][r4] - ls;
      }
    }
  }
}

// ---------------- fused edge head (prefetching, barrier-free) ----------------
__global__ __launch_bounds__(256) void k_edge(
    const unsigned short* __restrict__ zn_bf,
    const int* __restrict__ ci, const int* __restrict__ cj,
    const unsigned short* __restrict__ w1t, const float* __restrict__ b1,
    const unsigned short* __restrict__ w2t, const float* __restrict__ b2,
    const float* __restrict__ w3, const float* __restrict__ b3,
    float* __restrict__ out, int M) {
  __shared__ unsigned short h1s[4][16][136];
  int lane = threadIdx.x & 63, wave = threadIdx.x >> 6;
  int quad = lane >> 4, col = lane & 15;
  unsigned short (*h1)[136] = h1s[wave];
  int ntiles = (M + 63) >> 6;
  float b3v = b3[0];

  int tile = blockIdx.x;
  bf8_t afrag[4];
  if (tile < ntiles) {
    int r = tile * 64 + wave * 16 + col; if (r >= M) r = M - 1;
    const unsigned short* p0 = zn_bf + (size_t)ci[r] * 64;
    const unsigned short* p1 = zn_bf + (size_t)cj[r] * 64;
    afrag[0] = *(const bf8_t*)(p0 + quad * 8);
    afrag[1] = *(const bf8_t*)(p0 + 32 + quad * 8);
    afrag[2] = *(const bf8_t*)(p1 + quad * 8);
    afrag[3] = *(const bf8_t*)(p1 + 32 + quad * 8);
  }

  for (; tile < ntiles; tile += gridDim.x) {
    f4_t acc[8];
    #pragma unroll
    for (int nt = 0; nt < 8; ++nt) acc[nt] = (f4_t)0.f;
    #pragma unroll
    for (int s = 0; s < 4; ++s) {
      int kf = s * 32 + quad * 8;
      #pragma unroll
      for (int nt = 0; nt < 8; ++nt) {
        bf8_t b = *(const bf8_t*)(w1t + (size_t)(nt * 16 + col) * 128 + kf);
        acc[nt] = __builtin_amdgcn_mfma_f32_16x16x32_bf16(afrag[s], b, acc[nt], 0, 0, 0);
      }
    }

    int nxt = tile + gridDim.x;
    bf8_t nfrag[4];
    bool has_next = (nxt < ntiles);
    if (has_next) {
      int r = nxt * 64 + wave * 16 + col; if (r >= M) r = M - 1;
      const unsigned short* p0 = zn_bf + (size_t)ci[r] * 64;
      const unsigned short* p1 = zn_bf + (size_t)cj[r] * 64;
      nfrag[0] = *(const bf8_t*)(p0 + quad * 8);
      nfrag[1] = *(const bf8_t*)(p0 + 32 + quad * 8);
      nfrag[2] = *(const bf8_t*)(p1 + quad * 8);
      nfrag[3] = *(const bf8_t*)(p1 + 32 + quad * 8);
    }

    #pragma unroll
    for (int nt = 0; nt < 8; ++nt) {
      float bs = b1[nt * 16 + col];
      #pragma unroll
      for (int r4 = 0; r4 < 4; ++r4)
        h1[quad * 4 + r4][nt * 16 + col] = f2bf(gelu_f(acc[nt][r4] + bs));
    }

    f4_t a2[8];
    #pragma unroll
    for (int nt = 0; nt < 8; ++nt) a2[nt] = (f4_t)0.f;
    #pragma unroll
    for (int s = 0; s < 4; ++s) {
      int kc = s * 32 + quad * 8;
      bf8_t a0 = *(const bf8_t*)&h1[col][kc];
      #pragma unroll
      for (int nt = 0; nt < 8; ++nt) {
        bf8_t b = *(const bf8_t*)(w2t + (size_t)(nt * 16 + col) * 128 + kc);
        a2[nt] = __builtin_amdgcn_mfma_f32_16x16x32_bf16(a0, b, a2[nt], 0, 0, 0);
      }
    }
    float p[4] = {0.f, 0.f, 0.f, 0.f};
    #pragma unroll
    for (int nt = 0; nt < 8; ++nt) {
      float bs = b2[nt * 16 + col];
      float wv = w3[nt * 16 + col];
      #pragma unroll
      for (int r4 = 0; r4 < 4; ++r4)
        p[r4] += gelu_f(a2[nt][r4] + bs) * wv;
    }
    #pragma unroll
    for (int r4 = 0; r4 < 4; ++r4) {
      float s = p[r4];
      s += __shfl_xor(s, 1, 64);
      s += __shfl_xor(s, 2, 64);
      s += __shfl_xor(s, 4, 64);
      s += __shfl_xor(s, 8, 64);
      if (col == 0) {
        int row = tile * 64 + wave * 16 + quad * 4 + r4;
        if (row < M) out[row] = __builtin_amdgcn_rcpf(1.0f + __expf(-(s + b3v)));
      }
    }

    if (has_next) {
      afrag[0] = nfrag[0]; afrag[1] = nfrag[1];
      afrag[2] = nfrag[2]; afrag[3] = nfrag[3];
    }
  }
}

// ---------------- launcher ----------------
extern "C" void kernel_launch(void* const* d_in, const int* in_sizes, int n_in,
                              void* d_out, int out_size, void* d_ws, size_t ws_size,
                              hipStream_t stream) {
  const float* x_res  = (const float*)d_in[0];
  const float* Wl     = (const float*)d_in[1];
  const float* bl     = (const float*)d_in[2];
  const float* Wr     = (const float*)d_in[3];
  const float* gn_w   = (const float*)d_in[4];
  const float* gn_b   = (const float*)d_in[5];
  const float* gn_ms  = (const float*)d_in[6];
  const float* dyt1_w = (const float*)d_in[7];
  const float* dyt1_b = (const float*)d_in[8];
  const float* dyt1_a = (const float*)d_in[9];
  const float* lin1_w = (const float*)d_in[10];
  const float* lin1_b = (const float*)d_in[11];
  const float* lin2_w = (const float*)d_in[12];
  const float* lin2_b = (const float*)d_in[13];
  const float* lin3_w = (const float*)d_in[14];
  const float* lin3_b = (const float*)d_in[15];
  const float* dyt2_w = (const float*)d_in[16];
  const float* dyt2_b = (const float*)d_in[17];
  const float* dyt2_a = (const float*)d_in[18];
  const float* adyt1_w = (const float*)d_in[19];
  const float* adyt1_b = (const float*)d_in[20];
  const float* adyt1_a = (const float*)d_in[21];
  const float* aa1_w  = (const float*)d_in[22];
  const float* aa1_b  = (const float*)d_in[23];
  const float* aa2_w  = (const float*)d_in[24];
  const float* aa2_b  = (const float*)d_in[25];
  const float* aa3_w  = (const float*)d_in[26];
  const float* aa3_b  = (const float*)d_in[27];
  const float* adyt2_w = (const float*)d_in[28];
  const float* adyt2_b = (const float*)d_in[29];
  const float* adyt2_a = (const float*)d_in[30];
  const float* aa4_w  = (const float*)d_in[31];
  const float* aa4_b  = (const float*)d_in[32];
  const float* c1_w   = (const float*)d_in[33];
  const float* c1_b   = (const float*)d_in[34];
  const float* c2_w   = (const float*)d_in[35];
  const float* c2_b   = (const float*)d_in[36];
  const float* c3_w   = (const float*)d_in[37];
  const float* c3_b   = (const float*)d_in[38];
  const int*   edge   = (const int*)d_in[39];
  const int*   contact = (const int*)d_in[40];

  const size_t N = (size_t)Nn;
  const size_t ws_floats = ws_size / 4;

  float* ws    = (float*)d_ws;
  float* rdeg  = ws;
  float* hbuf  = rdeg + N;
  unsigned short* z_bf  = (unsigned short*)(hbuf + 64 * N);
  unsigned short* zn_bf = z_bf + 192 * N;
  float* stats = (float*)(zn_bf + 64 * N);
  unsigned short* wt_sage = (unsigned short*)(stats + 256);
  unsigned short* wt_lin1 = wt_sage + 3 * 64 * 128;
  unsigned short* wt_lin2 = wt_lin1 + 256 * 192;
  unsigned short* wt_lin3 = wt_lin2 + 256 * 256;
  unsigned short* wt_aa1  = wt_lin3 + 64 * 256;
  unsigned short* wt_aa2  = wt_aa1 + 256 * 128;
  unsigned short* wt_aa3  = wt_aa2 + 256 * 256;
  unsigned short* wt_aa4  = wt_aa3 + 256 * 256;
  unsigned short* wt_c1   = wt_aa4 + 32 * 256;
  unsigned short* wt_c2   = wt_c1 + 128 * 128;
  unsigned short* wt_end  = wt_c2 + 128 * 128;
  float* pool  = (float*)((((uintptr_t)wt_end + 15) & ~(uintptr_t)15));
  const size_t persist = (size_t)(pool - ws);

  const size_t gnn_need = 32 * N + N + (N + 1) + N + (size_t)Ee + 256;
  if (ws_floats < persist + gnn_need) return;

  unsigned short* agg_bf = (unsigned short*)pool;
  int* cnt     = (int*)(pool + 32 * N);
  int* rowptr  = cnt + N;
  int* cursor  = rowptr + N + 1;
  int* colidx  = cursor + N;
  int* bsum    = colidx + Ee;

  const int* esrc = edge;
  const int* edst = edge + Ee;

  // ---- CSR build ----
  hipMemsetAsync(cnt, 0, N * sizeof(int), stream);
  k_degi<<<(Ee + 255) / 256, 256, 0, stream>>>(edst, cnt, Ee);
  k_rdeg<<<(Nn + 255) / 256, 256, 0, stream>>>(cnt, rdeg, Nn);
  const int nb = (Nn + 1023) / 1024;
  k_scan1<<<nb, 256, 0, stream>>>(cnt, cursor, bsum, Nn);
  k_scan2<<<1, 256, 0, stream>>>(bsum, nb);
  k_scan3<<<(Nn + 255) / 256, 256, 0, stream>>>(cursor, bsum, rowptr, cursor, Nn, Ee);
  k_fill<<<(Ee + 255) / 256, 256, 0, stream>>>(esrc, edst, cursor, colidx, Ee);

  // ---- weight prep ----
  k_wtsage<<<(3 * 64 * 128 + 255) / 256, 256, 0, stream>>>(Wl, Wr, wt_sage);
  k_wt2<<<(256 * 192 + 255) / 256, 256, 0, stream>>>(lin1_w, wt_lin1, 192, 256, 256 * 192);
  k_wt2<<<(256 * 256 + 255) / 256, 256, 0, stream>>>(lin2_w, wt_lin2, 256, 256, 256 * 256);
  k_wt2<<<(64 * 256 + 255) / 256, 256, 0, stream>>>(lin3_w, wt_lin3, 256, 64, 64 * 256);
  k_wt2<<<(256 * 128 + 255) / 256, 256, 0, stream>>>(aa1_w, wt_aa1, 128, 256, 256 * 128);
  k_wt2<<<(256 * 256 + 255) / 256, 256, 0, stream>>>(aa2_w, wt_aa2, 256, 256, 256 * 256);
  k_wt2<<<(256 * 256 + 255) / 256, 256, 0, stream>>>(aa3_w, wt_aa3, 256, 256, 256 * 256);
  k_wt2<<<(32 * 256 + 255) / 256, 256, 0, stream>>>(aa4_w, wt_aa4, 256, 20, 32 * 256);
  k_wt2<<<(128 * 128 + 255) / 256, 256, 0, stream>>>(c1_w, wt_c1, 128, 128, 128 * 128);
  k_wt2<<<(128 * 128 + 255) / 256, 256, 0, stream>>>(c2_w, wt_c2, 128, 128, 128 * 128);

  // xb = bf16(x_res) in zn_bf slot
  k_cvt<<<(int)((N * 64 + 255) / 256), 256, 0, stream>>>(x_res, zn_bf, (int)(N * 64));

  // ---- GNN phase ----
  for (int l = 0; l < 3; ++l) {
    const unsigned short* xi = (l == 0) ? zn_bf : (z_bf + (size_t)(l - 1) * 64);
    int ldx = (l == 0) ? 64 : 192;
    hipMemsetAsync(stats, 0, 128 * sizeof(float), stream);
    k_gather<<<(Nn + 3) / 4, 256, 0, stream>>>(xi, ldx, rowptr, colidx, rdeg, agg_bf, Nn);
    mgemm<4><<<dim3((Nn + 127) / 128, 1), 256, 0, stream>>>(
        agg_bf, 64, xi, ldx, 64, 1,
        wt_sage + (size_t)l * 8192, bl + l * 64, hbuf, 64, 0, 1, Nn, 128, 64);
    k_stats<<<1024, 256, 0, stream>>>(hbuf, stats, Nn);
    k_statfin<<<1, 64, 0, stream>>>(stats, gn_ms + l * 64, Nn);
    k_norm<<<(Nn * 64) / 256, 256, 0, stream>>>(hbuf, stats, gn_w + l * 64, gn_b + l * 64,
                                                z_bf + (size_t)l * 64,
                                                (l > 0) ? (z_bf + (size_t)(l - 1) * 64) : nullptr, Nn);
  }

  // ---- block-cooperative fused node pipeline ----
  k_node<<<(Nn + 63) / 64, 256, 0, stream>>>(
      z_bf, x_res,
      dyt1_w, dyt1_b, dyt1_a, wt_lin1, lin1_b, wt_lin2, lin2_b, wt_lin3, lin3_b,
      dyt2_w, dyt2_b, dyt2_a,
      adyt1_w, adyt1_b, adyt1_a, wt_aa1, aa1_b, wt_aa2, aa2_b, wt_aa3, aa3_b,
      adyt2_w, adyt2_b, adyt2_a, wt_aa4, aa4_b,
      zn_bf, (float*)d_out, Nn);

  // ---- fused edge head ----
  float* eout = (float*)d_out + (size_t)Nn * 20;
  k_edge<<<2048, 256, 0, stream>>>(zn_bf, contact, contact + EPp,
      wt_c1, c1_b, wt_c2, c2_b, c3_w, c3_b, eout, EPp);
}